// Round 1
// baseline (3288.157 us; speedup 1.0000x reference)
//
#include <hip/hip_runtime.h>

#define NUSER 20000
#define NITEM 40000
#define NNODE 60000
#define DIM   64
#define NE    1000000   // per direction; total directed edges = 2*NE
#define KUSER 40
#define KITEM 10

// ---------------- degree / norm ----------------
__global__ __launch_bounds__(256) void k_count(const int* __restrict__ dst, int* __restrict__ cnt, int n) {
    int i = blockIdx.x * 256 + threadIdx.x;
    if (i < n) atomicAdd(&cnt[dst[i]], 1);
}

__global__ __launch_bounds__(256) void k_dinv(const int* __restrict__ cnt, float* __restrict__ dinv) {
    int i = blockIdx.x * 256 + threadIdx.x;
    if (i < NNODE) dinv[i] = 1.0f / sqrtf((float)(cnt[i] + 1));  // +1 self loop
}

// ---------------- tiled SGEMM: C = op(A@B + bias), A MxK, B KxN row-major ----------------
template<bool LRELU, bool BIAS>
__global__ __launch_bounds__(256) void sgemm(const float* __restrict__ A, const float* __restrict__ B,
                                             const float* __restrict__ bias, float* __restrict__ C,
                                             int M, int N, int K) {
    __shared__ float As[16][65];   // As[k][m]
    __shared__ float Bs[16][65];   // Bs[k][n]
    const int tid = threadIdx.x;
    const int tx = tid & 15, ty = tid >> 4;
    const int rowBase = blockIdx.y * 64, colBase = blockIdx.x * 64;
    float acc[4][4] = {};
    for (int k0 = 0; k0 < K; k0 += 16) {
        {   // A tile: 64 rows x 16 k, one float4 per thread
            int r = tid >> 2, c = (tid & 3) * 4;
            int gr = rowBase + r;
            float4 v = make_float4(0.f, 0.f, 0.f, 0.f);
            if (gr < M) v = *(const float4*)(A + (size_t)gr * K + k0 + c);
            As[c + 0][r] = v.x; As[c + 1][r] = v.y; As[c + 2][r] = v.z; As[c + 3][r] = v.w;
        }
        {   // B tile: 16 k x 64 cols
            int r = tid >> 4, c = (tid & 15) * 4;
            float4 v = *(const float4*)(B + (size_t)(k0 + r) * N + colBase + c);
            Bs[r][c + 0] = v.x; Bs[r][c + 1] = v.y; Bs[r][c + 2] = v.z; Bs[r][c + 3] = v.w;
        }
        __syncthreads();
        #pragma unroll
        for (int k = 0; k < 16; k++) {
            float a[4], b[4];
            #pragma unroll
            for (int i = 0; i < 4; i++) a[i] = As[k][ty * 4 + i];
            #pragma unroll
            for (int j = 0; j < 4; j++) b[j] = Bs[k][tx * 4 + j];
            #pragma unroll
            for (int i = 0; i < 4; i++)
                #pragma unroll
                for (int j = 0; j < 4; j++) acc[i][j] += a[i] * b[j];
        }
        __syncthreads();
    }
    const int gr0 = rowBase + ty * 4, gc = colBase + tx * 4;
    #pragma unroll
    for (int i = 0; i < 4; i++) {
        if (gr0 + i >= M) break;
        float4 v;
        float* vv = (float*)&v;
        #pragma unroll
        for (int j = 0; j < 4; j++) {
            float s = acc[i][j];
            if (BIAS) s += bias[gc + j];
            if (LRELU) s = s > 0.f ? s : 0.01f * s;
            vv[j] = s;
        }
        *(float4*)(C + (size_t)(gr0 + i) * N + gc) = v;
    }
}

// ---------------- misc elementwise ----------------
__global__ __launch_bounds__(256) void k_copy4(const float4* __restrict__ s, float4* __restrict__ d, int n4) {
    int i = blockIdx.x * 256 + threadIdx.x;
    if (i < n4) d[i] = s[i];
}

// row-wise L2 normalize, one wave per row of 64
__global__ __launch_bounds__(256) void k_l2n(float* __restrict__ x) {
    int row = blockIdx.x * 4 + (threadIdx.x >> 6);
    int lane = threadIdx.x & 63;
    if (row >= NNODE) return;
    float v = x[(size_t)row * 64 + lane];
    float ss = v * v;
    #pragma unroll
    for (int off = 32; off >= 1; off >>= 1) ss += __shfl_xor(ss, off, 64);
    float n = fmaxf(sqrtf(ss), 1e-12f);
    x[(size_t)row * 64 + lane] = v / n;
}

// y[i][c] = bias[c] + dinv[i]^2 * gw[i][c]   (self-loop term + bias)
__global__ __launch_bounds__(256) void k_conv_init(const float* __restrict__ gw, const float* __restrict__ dinv,
                                                   const float* __restrict__ bias, float* __restrict__ y) {
    int id = blockIdx.x * 256 + threadIdx.x;
    if (id >= NNODE * DIM) return;
    int r = id >> 6, c = id & 63;
    float di = dinv[r];
    y[id] = bias[c] + di * di * gw[id];
}

// wave-per-edge scatter: y[dst] += dinv[src]*dinv[dst] * gw[src]
__global__ __launch_bounds__(256) void k_scatter(const int* __restrict__ src, const int* __restrict__ dst,
                                                 const float* __restrict__ dinv, const float* __restrict__ gw,
                                                 float* __restrict__ y, int nE) {
    int e = (blockIdx.x * 256 + threadIdx.x) >> 6;
    int lane = threadIdx.x & 63;
    if (e >= nE) return;
    int s = src[e], d = dst[e];
    float w = dinv[s] * dinv[d];
    atomicAdd(&y[(size_t)d * 64 + lane], w * gw[(size_t)s * 64 + lane]);
}

// rep0[row][colOff + c] = (row<NUSER ? weight_u[row*2+wIdx] : 1) * (x+h+h1)
__global__ __launch_bounds__(256) void k_accum_rep(const float* __restrict__ x, const float* __restrict__ h,
                                                   const float* __restrict__ h1, const float* __restrict__ weight_u,
                                                   float* __restrict__ rep0, int colOff, int wIdx) {
    int id = blockIdx.x * 256 + threadIdx.x;
    if (id >= NNODE * DIM) return;
    int row = id >> 6, c = id & 63;
    float s = x[id] + h[id] + h1[id];
    float w = (row < NUSER) ? weight_u[row * 2 + wIdx] : 1.0f;
    rep0[(size_t)row * 128 + colOff + c] = w * s;
}

// out[u] = rep0[u] + sum_k uwm[u][k] * rep0[ug[u][k]]
__global__ __launch_bounds__(256) void k_user(const float* __restrict__ rep0, const int* __restrict__ ug,
                                              const float* __restrict__ uwm, float* __restrict__ out) {
    int id = blockIdx.x * 256 + threadIdx.x;
    if (id >= NUSER * 128) return;
    int u = id >> 7, d = id & 127;
    float acc = rep0[id];
    #pragma unroll 4
    for (int k = 0; k < KUSER; k++) {
        int nb = ug[u * KUSER + k];
        acc += uwm[u * KUSER + k] * rep0[(size_t)nb * 128 + d];
    }
    out[id] = acc;
}

// item-item propagation; rows of mm_indices are repeat(arange(NITEM), KITEM)
template<bool ADD_BASE>
__global__ __launch_bounds__(256) void k_item_prop(const float* __restrict__ srcrep, const int* __restrict__ col,
                                                   const float* __restrict__ vals, const float* __restrict__ base,
                                                   float* __restrict__ dstrep) {
    int id = blockIdx.x * 256 + threadIdx.x;
    if (id >= NITEM * 128) return;
    int r = id >> 7, d = id & 127;
    float acc = 0.f;
    #pragma unroll
    for (int j = 0; j < KITEM; j++) {
        int c = col[r * KITEM + j];
        acc += vals[r * KITEM + j] * srcrep[(size_t)c * 128 + d];
    }
    if (ADD_BASE) acc += base[id];
    dstrep[id] = acc;
}

extern "C" void kernel_launch(void* const* d_in, const int* in_sizes, int n_in,
                              void* d_out, int out_size, void* d_ws, size_t ws_size,
                              hipStream_t stream) {
    const int*   edge_index = (const int*)d_in[0];
    const float* v_feat   = (const float*)d_in[1];
    const float* t_feat   = (const float*)d_in[2];
    const float* v_pref   = (const float*)d_in[3];
    const float* t_pref   = (const float*)d_in[4];
    const float* v_mlp1_w = (const float*)d_in[5];
    const float* v_mlp1_b = (const float*)d_in[6];
    const float* v_mlp2_w = (const float*)d_in[7];
    const float* v_mlp2_b = (const float*)d_in[8];
    const float* t_mlp1_w = (const float*)d_in[9];
    const float* t_mlp1_b = (const float*)d_in[10];
    const float* t_mlp2_w = (const float*)d_in[11];
    const float* t_mlp2_b = (const float*)d_in[12];
    const float* v_conv_w = (const float*)d_in[13];
    const float* v_conv_b = (const float*)d_in[14];
    const float* t_conv_w = (const float*)d_in[15];
    const float* t_conv_b = (const float*)d_in[16];
    const float* weight_u = (const float*)d_in[17];
    const int*   user_graph = (const int*)d_in[18];
    const float* uwm      = (const float*)d_in[19];
    const int*   mm_indices = (const int*)d_in[20];
    const float* mm_values  = (const float*)d_in[21];
    float* out = (float*)d_out;

    // workspace layout
    char* wsb = (char*)d_ws;
    size_t off = 0;
    auto alloc = [&](size_t bytes) -> void* {
        void* p = wsb + off;
        off = (off + bytes + 255) & ~(size_t)255;
        return p;
    };
    int*   cnt  = (int*)  alloc(NNODE * 4);
    float* dinv = (float*)alloc(NNODE * 4);
    float* mid  = (float*)alloc((size_t)NITEM * 256 * 4);   // MLP hidden; reused for item-prop intermediate
    float* x    = (float*)alloc((size_t)NNODE * DIM * 4);
    float* h    = (float*)alloc((size_t)NNODE * DIM * 4);
    float* h1   = (float*)alloc((size_t)NNODE * DIM * 4);
    float* gw   = (float*)alloc((size_t)NNODE * DIM * 4);
    float* rep0 = (float*)alloc((size_t)NNODE * 128 * 4);
    (void)ws_size; (void)n_in; (void)in_sizes; (void)out_size;

    const int* e_src = edge_index;            // edge_index[0]
    const int* e_dst = edge_index + 2 * NE;   // edge_index[1]
    const int* mm_col = mm_indices + NITEM * KITEM;  // mm_indices[1]

    // degree / dinv
    hipMemsetAsync(cnt, 0, NNODE * 4, stream);
    k_count<<<(2 * NE + 255) / 256, 256, 0, stream>>>(e_dst, cnt, 2 * NE);
    k_dinv<<<(NNODE + 255) / 256, 256, 0, stream>>>(cnt, dinv);

    auto run_branch = [&](const float* feat, int featK, const float* pref,
                          const float* w1, const float* b1, const float* w2, const float* b2,
                          const float* cw, const float* cb, int colOff, int wIdx) {
        // MLP1: mid = lrelu(feat @ w1 + b1)   [NITEM x 256]
        {
            dim3 g(256 / 64, (NITEM + 63) / 64);
            sgemm<true, true><<<g, 256, 0, stream>>>(feat, w1, b1, mid, NITEM, 256, featK);
        }
        // MLP2 -> x rows NUSER.. : temp = mid @ w2 + b2   [NITEM x 64]
        {
            dim3 g(1, (NITEM + 63) / 64);
            sgemm<false, true><<<g, 256, 0, stream>>>(mid, w2, b2, x + (size_t)NUSER * DIM, NITEM, DIM, 256);
        }
        // pref -> x rows 0..NUSER
        k_copy4<<<(NUSER * DIM / 4 + 255) / 256, 256, 0, stream>>>((const float4*)pref, (float4*)x, NUSER * DIM / 4);
        // row L2 normalize
        k_l2n<<<(NNODE + 3) / 4, 256, 0, stream>>>(x);
        // conv1: h = A_hat (x @ cw) + cb
        {
            dim3 g(1, (NNODE + 63) / 64);
            sgemm<false, false><<<g, 256, 0, stream>>>(x, cw, nullptr, gw, NNODE, DIM, DIM);
        }
        k_conv_init<<<(NNODE * DIM + 255) / 256, 256, 0, stream>>>(gw, dinv, cb, h);
        k_scatter<<<(2 * NE * 64 + 255) / 256, 256, 0, stream>>>(e_src, e_dst, dinv, gw, h, 2 * NE);
        // conv2: h1 = A_hat (h @ cw) + cb
        {
            dim3 g(1, (NNODE + 63) / 64);
            sgemm<false, false><<<g, 256, 0, stream>>>(h, cw, nullptr, gw, NNODE, DIM, DIM);
        }
        k_conv_init<<<(NNODE * DIM + 255) / 256, 256, 0, stream>>>(gw, dinv, cb, h1);
        k_scatter<<<(2 * NE * 64 + 255) / 256, 256, 0, stream>>>(e_src, e_dst, dinv, gw, h1, 2 * NE);
        // rep0 contribution
        k_accum_rep<<<(NNODE * DIM + 255) / 256, 256, 0, stream>>>(x, h, h1, weight_u, rep0, colOff, wIdx);
    };

    run_branch(v_feat, 2048, v_pref, v_mlp1_w, v_mlp1_b, v_mlp2_w, v_mlp2_b, v_conv_w, v_conv_b, 0, 0);
    run_branch(t_feat, 768,  t_pref, t_mlp1_w, t_mlp1_b, t_mlp2_w, t_mlp2_b, t_conv_w, t_conv_b, 64, 1);

    // users: out rows 0..NUSER
    k_user<<<(NUSER * 128 + 255) / 256, 256, 0, stream>>>(rep0, user_graph, uwm, out);

    // items: 2-layer item-item propagation, out rows NUSER..
    const float* item0 = rep0 + (size_t)NUSER * 128;
    k_item_prop<false><<<(NITEM * 128 + 255) / 256, 256, 0, stream>>>(item0, mm_col, mm_values, nullptr, mid);
    k_item_prop<true><<<(NITEM * 128 + 255) / 256, 256, 0, stream>>>(mid, mm_col, mm_values, item0, out + (size_t)NUSER * 128);
}

// Round 2
// 1258.107 us; speedup vs baseline: 2.6136x; 2.6136x over previous
//
#include <hip/hip_runtime.h>

#define NUSER 20000
#define NITEM 40000
#define NNODE 60000
#define DIM   64
#define NE    1000000   // per direction; total directed edges = 2*NE
#define KUSER 40
#define KITEM 10

typedef __attribute__((ext_vector_type(8))) short short8v;
typedef __attribute__((ext_vector_type(4))) float floatx4;

__device__ inline short bf16rne(float f) {
    unsigned u = __builtin_bit_cast(unsigned, f);
    unsigned r = (u + 0x7fffu + ((u >> 16) & 1u)) >> 16;
    return (short)r;
}

// ---------------- degree / norm ----------------
__global__ __launch_bounds__(256) void k_count(const int* __restrict__ dst, int* __restrict__ cnt, int n) {
    int i = blockIdx.x * 256 + threadIdx.x;
    if (i < n) atomicAdd(&cnt[dst[i]], 1);
}

__global__ __launch_bounds__(256) void k_dinv(const int* __restrict__ cnt, float* __restrict__ dinv) {
    int i = blockIdx.x * 256 + threadIdx.x;
    if (i < NNODE) dinv[i] = 1.0f / sqrtf((float)(cnt[i] + 1));  // +1 self loop
}

// ---------------- exclusive scan (3-kernel) ----------------
__global__ __launch_bounds__(256) void k_scanA(const int* __restrict__ v, int* __restrict__ excl,
                                               int* __restrict__ bsum, int n) {
    __shared__ int s[256];
    int t = threadIdx.x, i = blockIdx.x * 256 + t;
    int orig = (i < n) ? v[i] : 0;
    s[t] = orig; __syncthreads();
    #pragma unroll
    for (int off = 1; off < 256; off <<= 1) {
        int u = (t >= off) ? s[t - off] : 0;
        __syncthreads();
        s[t] += u;
        __syncthreads();
    }
    if (i < n) excl[i] = s[t] - orig;
    if (t == 255) bsum[blockIdx.x] = s[255];
}

__global__ __launch_bounds__(256) void k_scanB(int* __restrict__ bsum, int nb) {
    __shared__ int s[256];
    int t = threadIdx.x;
    int orig = (t < nb) ? bsum[t] : 0;
    s[t] = orig; __syncthreads();
    #pragma unroll
    for (int off = 1; off < 256; off <<= 1) {
        int u = (t >= off) ? s[t - off] : 0;
        __syncthreads();
        s[t] += u;
        __syncthreads();
    }
    if (t < nb) bsum[t] = s[t] - orig;  // exclusive
}

__global__ __launch_bounds__(256) void k_scanC(int* __restrict__ excl, const int* __restrict__ bsum, int n) {
    int i = blockIdx.x * 256 + threadIdx.x;
    if (i < n) excl[i] += bsum[blockIdx.x];
    if (i == 0) excl[n] = 2 * NE;
}

__global__ __launch_bounds__(256) void k_copy_int(const int* __restrict__ s, int* __restrict__ d, int n) {
    int i = blockIdx.x * 256 + threadIdx.x;
    if (i < n) d[i] = s[i];
}

__global__ __launch_bounds__(256) void k_fill(const int* __restrict__ src, const int* __restrict__ dst,
                                              int* __restrict__ cursor, int* __restrict__ csr_src, int n) {
    int i = blockIdx.x * 256 + threadIdx.x;
    if (i >= n) return;
    int d = dst[i];
    int pos = atomicAdd(&cursor[d], 1);
    csr_src[pos] = src[i];
}

// ---------------- weight transpose + bf16 cast: Bt[n][k] = bf16(B[k][n]) ----------------
__global__ __launch_bounds__(256) void k_transpose_bf16(const float* __restrict__ B, short* __restrict__ Bt, int K) {
    __shared__ float s[16][17];
    int t = threadIdx.x, tx = t & 15, ty = t >> 4;
    int k0 = blockIdx.x * 16, n0 = blockIdx.y * 16;
    s[ty][tx] = B[(size_t)(k0 + ty) * 256 + n0 + tx];
    __syncthreads();
    Bt[(size_t)(n0 + ty) * K + k0 + tx] = bf16rne(s[tx][ty]);
}

// ---------------- MFMA MLP1: C = lrelu(A @ B + bias), A MxK f32, Bt 256xK bf16, C Mx256 f32 ----------------
__global__ __launch_bounds__(512) void mfma_mlp1(const float* __restrict__ A, const short* __restrict__ Bt,
                                                 const float* __restrict__ bias, float* __restrict__ C,
                                                 int M, int K) {
    __shared__ short Alds[128 * 32];
    const int tid = threadIdx.x;
    const int lane = tid & 63, wid = tid >> 6;
    const int wr = wid >> 2, wc = wid & 3;        // 2 x 4 waves -> 64x64 tiles of 128x256
    const int rowBase = blockIdx.x * 128;

    // staging: thread t loads 8 floats of row (t>>2), k-chunk (t&3)*8
    const int srow = tid >> 2;
    const int skc = (tid & 3) * 8;
    int agrow = rowBase + srow; if (agrow >= M) agrow = M - 1;  // clamp (stores are guarded)
    const float* aptr = A + (size_t)agrow * K + skc;

    const int ar_off = (wr * 64 + (lane & 15)) * 32 + (lane >> 4) * 8;
    const int bcol0 = wc * 64 + (lane & 15);
    const int kg8 = (lane >> 4) * 8;

    floatx4 acc[4][4];
    #pragma unroll
    for (int m = 0; m < 4; m++)
        #pragma unroll
        for (int n = 0; n < 4; n++) acc[m][n] = (floatx4)0.f;

    float4 pre0 = *(const float4*)(aptr);
    float4 pre1 = *(const float4*)(aptr + 4);

    const int nk = K >> 5;
    for (int ks = 0; ks < nk; ++ks) {
        short8v as;
        as[0] = bf16rne(pre0.x); as[1] = bf16rne(pre0.y); as[2] = bf16rne(pre0.z); as[3] = bf16rne(pre0.w);
        as[4] = bf16rne(pre1.x); as[5] = bf16rne(pre1.y); as[6] = bf16rne(pre1.z); as[7] = bf16rne(pre1.w);
        *(short8v*)&Alds[srow * 32 + skc] = as;
        __syncthreads();
        if (ks + 1 < nk) {  // prefetch next A chunk (hides HBM latency under MFMA)
            const float* ap = aptr + (ks + 1) * 32;
            pre0 = *(const float4*)(ap);
            pre1 = *(const float4*)(ap + 4);
        }
        short8v a[4], b[4];
        #pragma unroll
        for (int n = 0; n < 4; n++)
            b[n] = *(const short8v*)(Bt + (size_t)(bcol0 + n * 16) * K + ks * 32 + kg8);
        #pragma unroll
        for (int m = 0; m < 4; m++)
            a[m] = *(const short8v*)&Alds[ar_off + m * 16 * 32];
        #pragma unroll
        for (int m = 0; m < 4; m++)
            #pragma unroll
            for (int n = 0; n < 4; n++)
                acc[m][n] = __builtin_amdgcn_mfma_f32_16x16x32_bf16(a[m], b[n], acc[m][n], 0, 0, 0);
        __syncthreads();
    }
    // epilogue: bias + leaky-relu; C/D layout col=lane&15, row=(lane>>4)*4+reg
    const int c0 = wc * 64 + (lane & 15);
    #pragma unroll
    for (int n = 0; n < 4; n++) {
        float bn = bias[c0 + n * 16];
        #pragma unroll
        for (int m = 0; m < 4; m++) {
            int r0 = rowBase + wr * 64 + m * 16 + (lane >> 4) * 4;
            #pragma unroll
            for (int q = 0; q < 4; q++) {
                int r = r0 + q;
                if (r < M) {
                    float v = acc[m][n][q] + bn;
                    C[(size_t)r * 256 + c0 + n * 16] = v > 0.f ? v : 0.01f * v;
                }
            }
        }
    }
}

// ---------------- tiled SGEMM (kept for MLP2 / conv GEMMs) ----------------
template<bool LRELU, bool BIAS>
__global__ __launch_bounds__(256) void sgemm(const float* __restrict__ A, const float* __restrict__ B,
                                             const float* __restrict__ bias, float* __restrict__ C,
                                             int M, int N, int K) {
    __shared__ float As[16][65];
    __shared__ float Bs[16][65];
    const int tid = threadIdx.x;
    const int tx = tid & 15, ty = tid >> 4;
    const int rowBase = blockIdx.y * 64, colBase = blockIdx.x * 64;
    float acc[4][4] = {};
    for (int k0 = 0; k0 < K; k0 += 16) {
        {
            int r = tid >> 2, c = (tid & 3) * 4;
            int gr = rowBase + r;
            float4 v = make_float4(0.f, 0.f, 0.f, 0.f);
            if (gr < M) v = *(const float4*)(A + (size_t)gr * K + k0 + c);
            As[c + 0][r] = v.x; As[c + 1][r] = v.y; As[c + 2][r] = v.z; As[c + 3][r] = v.w;
        }
        {
            int r = tid >> 4, c = (tid & 15) * 4;
            float4 v = *(const float4*)(B + (size_t)(k0 + r) * N + colBase + c);
            Bs[r][c + 0] = v.x; Bs[r][c + 1] = v.y; Bs[r][c + 2] = v.z; Bs[r][c + 3] = v.w;
        }
        __syncthreads();
        #pragma unroll
        for (int k = 0; k < 16; k++) {
            float a[4], b[4];
            #pragma unroll
            for (int i = 0; i < 4; i++) a[i] = As[k][ty * 4 + i];
            #pragma unroll
            for (int j = 0; j < 4; j++) b[j] = Bs[k][tx * 4 + j];
            #pragma unroll
            for (int i = 0; i < 4; i++)
                #pragma unroll
                for (int j = 0; j < 4; j++) acc[i][j] += a[i] * b[j];
        }
        __syncthreads();
    }
    const int gr0 = rowBase + ty * 4, gc = colBase + tx * 4;
    #pragma unroll
    for (int i = 0; i < 4; i++) {
        if (gr0 + i >= M) break;
        float4 v;
        float* vv = (float*)&v;
        #pragma unroll
        for (int j = 0; j < 4; j++) {
            float s = acc[i][j];
            if (BIAS) s += bias[gc + j];
            if (LRELU) s = s > 0.f ? s : 0.01f * s;
            vv[j] = s;
        }
        *(float4*)(C + (size_t)(gr0 + i) * N + gc) = v;
    }
}

// ---------------- misc ----------------
__global__ __launch_bounds__(256) void k_copy4(const float4* __restrict__ s, float4* __restrict__ d, int n4) {
    int i = blockIdx.x * 256 + threadIdx.x;
    if (i < n4) d[i] = s[i];
}

__global__ __launch_bounds__(256) void k_l2n(float* __restrict__ x) {
    int row = blockIdx.x * 4 + (threadIdx.x >> 6);
    int lane = threadIdx.x & 63;
    if (row >= NNODE) return;
    float v = x[(size_t)row * 64 + lane];
    float ss = v * v;
    #pragma unroll
    for (int off = 32; off >= 1; off >>= 1) ss += __shfl_xor(ss, off, 64);
    float n = fmaxf(sqrtf(ss), 1e-12f);
    x[(size_t)row * 64 + lane] = v / n;
}

// CSR gather conv: y[r] = cb + dinv[r]*(dinv[r]*gw[r] + sum_{e in row r} dinv[s_e]*gw[s_e])
__global__ __launch_bounds__(256) void k_gather(const int* __restrict__ rowptr, const int* __restrict__ csr_src,
                                                const float* __restrict__ dinv, const float* __restrict__ gw,
                                                const float* __restrict__ cb, float* __restrict__ y) {
    int row = blockIdx.x * 4 + (threadIdx.x >> 6);
    int lane = threadIdx.x & 63;
    if (row >= NNODE) return;
    int p0 = rowptr[row], p1 = rowptr[row + 1];
    float dr = dinv[row];
    float acc = dr * gw[(size_t)row * 64 + lane];   // self loop
    for (int p = p0; p < p1; p += 64) {
        int c = p1 - p; if (c > 64) c = 64;
        int s = (lane < c) ? csr_src[p + lane] : 0;
        float w = (lane < c) ? dinv[s] : 0.f;
        #pragma unroll 4
        for (int j = 0; j < c; ++j) {
            int sj = __shfl(s, j, 64);
            float wj = __shfl(w, j, 64);
            acc += wj * gw[(size_t)sj * 64 + lane];
        }
    }
    y[(size_t)row * 64 + lane] = cb[lane] + dr * acc;
}

__global__ __launch_bounds__(256) void k_accum_rep(const float* __restrict__ x, const float* __restrict__ h,
                                                   const float* __restrict__ h1, const float* __restrict__ weight_u,
                                                   float* __restrict__ rep0, int colOff, int wIdx) {
    int id = blockIdx.x * 256 + threadIdx.x;
    if (id >= NNODE * DIM) return;
    int row = id >> 6, c = id & 63;
    float s = x[id] + h[id] + h1[id];
    float w = (row < NUSER) ? weight_u[row * 2 + wIdx] : 1.0f;
    rep0[(size_t)row * 128 + colOff + c] = w * s;
}

__global__ __launch_bounds__(256) void k_user(const float* __restrict__ rep0, const int* __restrict__ ug,
                                              const float* __restrict__ uwm, float* __restrict__ out) {
    int id = blockIdx.x * 256 + threadIdx.x;
    if (id >= NUSER * 128) return;
    int u = id >> 7, d = id & 127;
    float acc = rep0[id];
    #pragma unroll 4
    for (int k = 0; k < KUSER; k++) {
        int nb = ug[u * KUSER + k];
        acc += uwm[u * KUSER + k] * rep0[(size_t)nb * 128 + d];
    }
    out[id] = acc;
}

template<bool ADD_BASE>
__global__ __launch_bounds__(256) void k_item_prop(const float* __restrict__ srcrep, const int* __restrict__ col,
                                                   const float* __restrict__ vals, const float* __restrict__ base,
                                                   float* __restrict__ dstrep) {
    int id = blockIdx.x * 256 + threadIdx.x;
    if (id >= NITEM * 128) return;
    int r = id >> 7, d = id & 127;
    float acc = 0.f;
    #pragma unroll
    for (int j = 0; j < KITEM; j++) {
        int c = col[r * KITEM + j];
        acc += vals[r * KITEM + j] * srcrep[(size_t)c * 128 + d];
    }
    if (ADD_BASE) acc += base[id];
    dstrep[id] = acc;
}

extern "C" void kernel_launch(void* const* d_in, const int* in_sizes, int n_in,
                              void* d_out, int out_size, void* d_ws, size_t ws_size,
                              hipStream_t stream) {
    const int*   edge_index = (const int*)d_in[0];
    const float* v_feat   = (const float*)d_in[1];
    const float* t_feat   = (const float*)d_in[2];
    const float* v_pref   = (const float*)d_in[3];
    const float* t_pref   = (const float*)d_in[4];
    const float* v_mlp1_w = (const float*)d_in[5];
    const float* v_mlp1_b = (const float*)d_in[6];
    const float* v_mlp2_w = (const float*)d_in[7];
    const float* v_mlp2_b = (const float*)d_in[8];
    const float* t_mlp1_w = (const float*)d_in[9];
    const float* t_mlp1_b = (const float*)d_in[10];
    const float* t_mlp2_w = (const float*)d_in[11];
    const float* t_mlp2_b = (const float*)d_in[12];
    const float* v_conv_w = (const float*)d_in[13];
    const float* v_conv_b = (const float*)d_in[14];
    const float* t_conv_w = (const float*)d_in[15];
    const float* t_conv_b = (const float*)d_in[16];
    const float* weight_u = (const float*)d_in[17];
    const int*   user_graph = (const int*)d_in[18];
    const float* uwm      = (const float*)d_in[19];
    const int*   mm_indices = (const int*)d_in[20];
    const float* mm_values  = (const float*)d_in[21];
    float* out = (float*)d_out;

    char* wsb = (char*)d_ws;
    size_t off = 0;
    auto alloc = [&](size_t bytes) -> void* {
        void* p = wsb + off;
        off = (off + bytes + 255) & ~(size_t)255;
        return p;
    };
    int*   cnt     = (int*)  alloc(NNODE * 4);          // later reused as CSR fill cursor
    float* dinv    = (float*)alloc(NNODE * 4);
    int*   rowptr  = (int*)  alloc((NNODE + 1) * 4);
    int*   bsum    = (int*)  alloc(256 * 4);
    int*   csr_src = (int*)  alloc((size_t)2 * NE * 4);
    short* Btw     = (short*)alloc((size_t)256 * 2048 * 2);
    float* mid     = (float*)alloc((size_t)NITEM * 256 * 4);
    float* x       = (float*)alloc((size_t)NNODE * DIM * 4);
    float* h       = (float*)alloc((size_t)NNODE * DIM * 4);
    float* h1      = (float*)alloc((size_t)NNODE * DIM * 4);
    float* gw      = (float*)alloc((size_t)NNODE * DIM * 4);
    float* rep0    = (float*)alloc((size_t)NNODE * 128 * 4);
    (void)ws_size; (void)n_in; (void)in_sizes; (void)out_size;

    const int* e_src = edge_index;
    const int* e_dst = edge_index + 2 * NE;
    const int* mm_col = mm_indices + NITEM * KITEM;

    const int NB = (NNODE + 255) / 256;   // 235

    // degree + dinv
    hipMemsetAsync(cnt, 0, NNODE * 4, stream);
    k_count<<<(2 * NE + 255) / 256, 256, 0, stream>>>(e_dst, cnt, 2 * NE);
    k_dinv<<<(NNODE + 255) / 256, 256, 0, stream>>>(cnt, dinv);

    // CSR build: exclusive scan of cnt -> rowptr, then atomic-cursor fill
    k_scanA<<<NB, 256, 0, stream>>>(cnt, rowptr, bsum, NNODE);
    k_scanB<<<1, 256, 0, stream>>>(bsum, NB);
    k_scanC<<<NB, 256, 0, stream>>>(rowptr, bsum, NNODE);
    k_copy_int<<<NB, 256, 0, stream>>>(rowptr, cnt, NNODE);   // cursor = cnt buffer
    k_fill<<<(2 * NE + 255) / 256, 256, 0, stream>>>(e_src, e_dst, cnt, csr_src, 2 * NE);

    auto run_branch = [&](const float* feat, int featK, const float* pref,
                          const float* w1, const float* b1, const float* w2, const float* b2,
                          const float* cw, const float* cb, int colOff, int wIdx) {
        // MLP1 via MFMA: mid = lrelu(feat @ w1 + b1)
        {
            dim3 tg(featK / 16, 16);
            k_transpose_bf16<<<tg, 256, 0, stream>>>(w1, Btw, featK);
            mfma_mlp1<<<(NITEM + 127) / 128, 512, 0, stream>>>(feat, Btw, b1, mid, NITEM, featK);
        }
        // MLP2: x rows NUSER.. = mid @ w2 + b2
        {
            dim3 g(1, (NITEM + 63) / 64);
            sgemm<false, true><<<g, 256, 0, stream>>>(mid, w2, b2, x + (size_t)NUSER * DIM, NITEM, DIM, 256);
        }
        k_copy4<<<(NUSER * DIM / 4 + 255) / 256, 256, 0, stream>>>((const float4*)pref, (float4*)x, NUSER * DIM / 4);
        k_l2n<<<(NNODE + 3) / 4, 256, 0, stream>>>(x);
        // conv1
        {
            dim3 g(1, (NNODE + 63) / 64);
            sgemm<false, false><<<g, 256, 0, stream>>>(x, cw, nullptr, gw, NNODE, DIM, DIM);
        }
        k_gather<<<(NNODE + 3) / 4, 256, 0, stream>>>(rowptr, csr_src, dinv, gw, cb, h);
        // conv2
        {
            dim3 g(1, (NNODE + 63) / 64);
            sgemm<false, false><<<g, 256, 0, stream>>>(h, cw, nullptr, gw, NNODE, DIM, DIM);
        }
        k_gather<<<(NNODE + 3) / 4, 256, 0, stream>>>(rowptr, csr_src, dinv, gw, cb, h1);
        k_accum_rep<<<(NNODE * DIM + 255) / 256, 256, 0, stream>>>(x, h, h1, weight_u, rep0, colOff, wIdx);
    };

    run_branch(v_feat, 2048, v_pref, v_mlp1_w, v_mlp1_b, v_mlp2_w, v_mlp2_b, v_conv_w, v_conv_b, 0, 0);
    run_branch(t_feat, 768,  t_pref, t_mlp1_w, t_mlp1_b, t_mlp2_w, t_mlp2_b, t_conv_w, t_conv_b, 64, 1);

    k_user<<<(NUSER * 128 + 255) / 256, 256, 0, stream>>>(rep0, user_graph, uwm, out);

    const float* item0 = rep0 + (size_t)NUSER * 128;
    k_item_prop<false><<<(NITEM * 128 + 255) / 256, 256, 0, stream>>>(item0, mm_col, mm_values, nullptr, mid);
    k_item_prop<true><<<(NITEM * 128 + 255) / 256, 256, 0, stream>>>(mid, mm_col, mm_values, item0, out + (size_t)NUSER * 128);
}

// Round 3
// 1159.331 us; speedup vs baseline: 2.8363x; 1.0852x over previous
//
#include <hip/hip_runtime.h>

#define NUSER 20000
#define NITEM 40000
#define NNODE 60000
#define DIM   64
#define NE    1000000   // per direction; total directed edges = 2*NE
#define KUSER 40
#define KITEM 10

typedef __attribute__((ext_vector_type(8))) short short8v;
typedef __attribute__((ext_vector_type(4))) float floatx4;

__device__ inline short bf16rne(float f) {
    unsigned u = __builtin_bit_cast(unsigned, f);
    unsigned r = (u + 0x7fffu + ((u >> 16) & 1u)) >> 16;
    return (short)r;
}

// ---------------- degree / norm ----------------
__global__ __launch_bounds__(256) void k_count(const int* __restrict__ dst, int* __restrict__ cnt, int n) {
    int i = blockIdx.x * 256 + threadIdx.x;
    if (i < n) atomicAdd(&cnt[dst[i]], 1);
}

__global__ __launch_bounds__(256) void k_dinv(const int* __restrict__ cnt, float* __restrict__ dinv) {
    int i = blockIdx.x * 256 + threadIdx.x;
    if (i < NNODE) dinv[i] = 1.0f / sqrtf((float)(cnt[i] + 1));  // +1 self loop
}

// ---------------- exclusive scan (3-kernel) ----------------
__global__ __launch_bounds__(256) void k_scanA(const int* __restrict__ v, int* __restrict__ excl,
                                               int* __restrict__ bsum, int n) {
    __shared__ int s[256];
    int t = threadIdx.x, i = blockIdx.x * 256 + t;
    int orig = (i < n) ? v[i] : 0;
    s[t] = orig; __syncthreads();
    #pragma unroll
    for (int off = 1; off < 256; off <<= 1) {
        int u = (t >= off) ? s[t - off] : 0;
        __syncthreads();
        s[t] += u;
        __syncthreads();
    }
    if (i < n) excl[i] = s[t] - orig;
    if (t == 255) bsum[blockIdx.x] = s[255];
}

__global__ __launch_bounds__(256) void k_scanB(int* __restrict__ bsum, int nb) {
    __shared__ int s[256];
    int t = threadIdx.x;
    int orig = (t < nb) ? bsum[t] : 0;
    s[t] = orig; __syncthreads();
    #pragma unroll
    for (int off = 1; off < 256; off <<= 1) {
        int u = (t >= off) ? s[t - off] : 0;
        __syncthreads();
        s[t] += u;
        __syncthreads();
    }
    if (t < nb) bsum[t] = s[t] - orig;  // exclusive
}

__global__ __launch_bounds__(256) void k_scanC(int* __restrict__ excl, const int* __restrict__ bsum, int n) {
    int i = blockIdx.x * 256 + threadIdx.x;
    if (i < n) excl[i] += bsum[blockIdx.x];
    if (i == 0) excl[n] = 2 * NE;
}

__global__ __launch_bounds__(256) void k_copy_int(const int* __restrict__ s, int* __restrict__ d, int n) {
    int i = blockIdx.x * 256 + threadIdx.x;
    if (i < n) d[i] = s[i];
}

__global__ __launch_bounds__(256) void k_fill(const int* __restrict__ src, const int* __restrict__ dst,
                                              int* __restrict__ cursor, int* __restrict__ csr_src, int n) {
    int i = blockIdx.x * 256 + threadIdx.x;
    if (i >= n) return;
    int d = dst[i];
    int pos = atomicAdd(&cursor[d], 1);
    csr_src[pos] = src[i];
}

// ---------------- weight transpose + bf16 cast, k-blocked: Btb[k/32][n][k%32] ----------------
__global__ __launch_bounds__(256) void k_transpose_bf16(const float* __restrict__ B, short* __restrict__ Btb, int K) {
    __shared__ float s[16][17];
    int t = threadIdx.x, tx = t & 15, ty = t >> 4;
    int k0 = blockIdx.x * 16, n0 = blockIdx.y * 16;
    s[ty][tx] = B[(size_t)(k0 + ty) * 256 + n0 + tx];
    __syncthreads();
    int k = k0 + tx, n = n0 + ty;
    Btb[(size_t)(k >> 5) * 8192 + n * 32 + (k & 31)] = bf16rne(s[tx][ty]);
}

// ---------------- MFMA MLP1: C = lrelu(A @ B + bias) ----------------
// A: MxK f32.  Btb: k-blocked bf16 [K/32][256][32].  C: Mx256 f32.
// Block = 64 rows x 256 cols, 4 waves (each 64x64), K-step 32, double-buffered LDS.
#define APAD 36   // rows padded to 36 shorts (72B stride -> <=2-way bank alias, free)
__global__ __launch_bounds__(256) void mfma_mlp1(const float* __restrict__ A, const short* __restrict__ Btb,
                                                 const float* __restrict__ bias, float* __restrict__ C,
                                                 int M, int K) {
    __shared__ short As[2][64 * APAD];
    __shared__ short Bs[2][256 * APAD];
    const int tid = threadIdx.x;
    const int lane = tid & 63, wc = tid >> 6;     // 4 waves across N
    const int rowBase = blockIdx.x * 64;

    // A staging: thread t -> row t>>2, k-chunk (t&3)*8 (8 f32 -> 8 bf16)
    const int sar = tid >> 2, sac = (tid & 3) * 8;
    int arow = rowBase + sar; if (arow >= M) arow = M - 1;
    const float* aptr = A + (size_t)arow * K + sac;

    // fragment offsets (shorts)
    const int fk = (lane >> 4) * 8;
    const int faoff = (lane & 15) * APAD + fk;
    const int fboff = (wc * 64 + (lane & 15)) * APAD + fk;

    floatx4 acc[4][4];
    #pragma unroll
    for (int m = 0; m < 4; m++)
        #pragma unroll
        for (int n = 0; n < 4; n++) acc[m][n] = (floatx4)0.f;

    float4 ra0, ra1;
    short8v rb[4];
    const int nk = K >> 5;

    auto ldg = [&](int ks) {
        const float* ap = aptr + ks * 32;
        ra0 = *(const float4*)(ap);
        ra1 = *(const float4*)(ap + 4);
        const short* bsrc = Btb + (size_t)ks * 8192 + tid * 8;
        #pragma unroll
        for (int it = 0; it < 4; it++) rb[it] = *(const short8v*)(bsrc + it * 2048);
    };
    auto stv = [&](int buf) {
        short8v av;
        av[0] = bf16rne(ra0.x); av[1] = bf16rne(ra0.y); av[2] = bf16rne(ra0.z); av[3] = bf16rne(ra0.w);
        av[4] = bf16rne(ra1.x); av[5] = bf16rne(ra1.y); av[6] = bf16rne(ra1.z); av[7] = bf16rne(ra1.w);
        *(short8v*)&As[buf][sar * APAD + sac] = av;
        #pragma unroll
        for (int it = 0; it < 4; it++)
            *(short8v*)&Bs[buf][(sar + it * 64) * APAD + sac] = rb[it];
    };

    ldg(0); stv(0);
    __syncthreads();
    int cur = 0;
    for (int ks = 0; ks < nk; ++ks) {
        if (ks + 1 < nk) ldg(ks + 1);
        short8v a[4], b[4];
        #pragma unroll
        for (int m = 0; m < 4; m++) a[m] = *(const short8v*)&As[cur][faoff + m * 16 * APAD];
        #pragma unroll
        for (int n = 0; n < 4; n++) b[n] = *(const short8v*)&Bs[cur][fboff + n * 16 * APAD];
        #pragma unroll
        for (int m = 0; m < 4; m++)
            #pragma unroll
            for (int n = 0; n < 4; n++)
                acc[m][n] = __builtin_amdgcn_mfma_f32_16x16x32_bf16(a[m], b[n], acc[m][n], 0, 0, 0);
        if (ks + 1 < nk) stv(cur ^ 1);
        __syncthreads();
        cur ^= 1;
    }

    // epilogue: bias + leaky-relu; C/D layout col=lane&15, row=(lane>>4)*4+reg
    const int c0 = wc * 64 + (lane & 15);
    #pragma unroll
    for (int n = 0; n < 4; n++) {
        float bn = bias[c0 + n * 16];
        #pragma unroll
        for (int m = 0; m < 4; m++) {
            int r0 = rowBase + m * 16 + (lane >> 4) * 4;
            #pragma unroll
            for (int q = 0; q < 4; q++) {
                int r = r0 + q;
                if (r < M) {
                    float v = acc[m][n][q] + bn;
                    C[(size_t)r * 256 + c0 + n * 16] = v > 0.f ? v : 0.01f * v;
                }
            }
        }
    }
}

// ---------------- tiled SGEMM (MLP2 / conv GEMMs, fp32) ----------------
template<bool LRELU, bool BIAS>
__global__ __launch_bounds__(256) void sgemm(const float* __restrict__ A, const float* __restrict__ B,
                                             const float* __restrict__ bias, float* __restrict__ C,
                                             int M, int N, int K) {
    __shared__ float As[16][65];
    __shared__ float Bs[16][65];
    const int tid = threadIdx.x;
    const int tx = tid & 15, ty = tid >> 4;
    const int rowBase = blockIdx.y * 64, colBase = blockIdx.x * 64;
    float acc[4][4] = {};
    for (int k0 = 0; k0 < K; k0 += 16) {
        {
            int r = tid >> 2, c = (tid & 3) * 4;
            int gr = rowBase + r;
            float4 v = make_float4(0.f, 0.f, 0.f, 0.f);
            if (gr < M) v = *(const float4*)(A + (size_t)gr * K + k0 + c);
            As[c + 0][r] = v.x; As[c + 1][r] = v.y; As[c + 2][r] = v.z; As[c + 3][r] = v.w;
        }
        {
            int r = tid >> 4, c = (tid & 15) * 4;
            float4 v = *(const float4*)(B + (size_t)(k0 + r) * N + colBase + c);
            Bs[r][c + 0] = v.x; Bs[r][c + 1] = v.y; Bs[r][c + 2] = v.z; Bs[r][c + 3] = v.w;
        }
        __syncthreads();
        #pragma unroll
        for (int k = 0; k < 16; k++) {
            float a[4], b[4];
            #pragma unroll
            for (int i = 0; i < 4; i++) a[i] = As[k][ty * 4 + i];
            #pragma unroll
            for (int j = 0; j < 4; j++) b[j] = Bs[k][tx * 4 + j];
            #pragma unroll
            for (int i = 0; i < 4; i++)
                #pragma unroll
                for (int j = 0; j < 4; j++) acc[i][j] += a[i] * b[j];
        }
        __syncthreads();
    }
    const int gr0 = rowBase + ty * 4, gc = colBase + tx * 4;
    #pragma unroll
    for (int i = 0; i < 4; i++) {
        if (gr0 + i >= M) break;
        float4 v;
        float* vv = (float*)&v;
        #pragma unroll
        for (int j = 0; j < 4; j++) {
            float s = acc[i][j];
            if (BIAS) s += bias[gc + j];
            if (LRELU) s = s > 0.f ? s : 0.01f * s;
            vv[j] = s;
        }
        *(float4*)(C + (size_t)(gr0 + i) * N + gc) = v;
    }
}

// ---------------- misc ----------------
__global__ __launch_bounds__(256) void k_copy4(const float4* __restrict__ s, float4* __restrict__ d, int n4) {
    int i = blockIdx.x * 256 + threadIdx.x;
    if (i < n4) d[i] = s[i];
}

__global__ __launch_bounds__(256) void k_l2n(float* __restrict__ x) {
    int row = blockIdx.x * 4 + (threadIdx.x >> 6);
    int lane = threadIdx.x & 63;
    if (row >= NNODE) return;
    float v = x[(size_t)row * 64 + lane];
    float ss = v * v;
    #pragma unroll
    for (int off = 32; off >= 1; off >>= 1) ss += __shfl_xor(ss, off, 64);
    float n = fmaxf(sqrtf(ss), 1e-12f);
    x[(size_t)row * 64 + lane] = v / n;
}

// CSR gather conv: y[r] = cb + dinv[r]*(dinv[r]*gw[r] + sum_{e in row r} dinv[s_e]*gw[s_e])
__global__ __launch_bounds__(256) void k_gather(const int* __restrict__ rowptr, const int* __restrict__ csr_src,
                                                const float* __restrict__ dinv, const float* __restrict__ gw,
                                                const float* __restrict__ cb, float* __restrict__ y) {
    int row = blockIdx.x * 4 + (threadIdx.x >> 6);
    int lane = threadIdx.x & 63;
    if (row >= NNODE) return;
    int p0 = rowptr[row], p1 = rowptr[row + 1];
    float dr = dinv[row];
    float acc = dr * gw[(size_t)row * 64 + lane];   // self loop
    for (int p = p0; p < p1; p += 64) {
        int c = p1 - p; if (c > 64) c = 64;
        int s = (lane < c) ? csr_src[p + lane] : 0;
        float w = (lane < c) ? dinv[s] : 0.f;
        #pragma unroll 4
        for (int j = 0; j < c; ++j) {
            int sj = __shfl(s, j, 64);
            float wj = __shfl(w, j, 64);
            acc += wj * gw[(size_t)sj * 64 + lane];
        }
    }
    y[(size_t)row * 64 + lane] = cb[lane] + dr * acc;
}

__global__ __launch_bounds__(256) void k_accum_rep(const float* __restrict__ x, const float* __restrict__ h,
                                                   const float* __restrict__ h1, const float* __restrict__ weight_u,
                                                   float* __restrict__ rep0, int colOff, int wIdx) {
    int id = blockIdx.x * 256 + threadIdx.x;
    if (id >= NNODE * DIM) return;
    int row = id >> 6, c = id & 63;
    float s = x[id] + h[id] + h1[id];
    float w = (row < NUSER) ? weight_u[row * 2 + wIdx] : 1.0f;
    rep0[(size_t)row * 128 + colOff + c] = w * s;
}

__global__ __launch_bounds__(256) void k_user(const float* __restrict__ rep0, const int* __restrict__ ug,
                                              const float* __restrict__ uwm, float* __restrict__ out) {
    int id = blockIdx.x * 256 + threadIdx.x;
    if (id >= NUSER * 128) return;
    int u = id >> 7, d = id & 127;
    float acc = rep0[id];
    #pragma unroll 4
    for (int k = 0; k < KUSER; k++) {
        int nb = ug[u * KUSER + k];
        acc += uwm[u * KUSER + k] * rep0[(size_t)nb * 128 + d];
    }
    out[id] = acc;
}

template<bool ADD_BASE>
__global__ __launch_bounds__(256) void k_item_prop(const float* __restrict__ srcrep, const int* __restrict__ col,
                                                   const float* __restrict__ vals, const float* __restrict__ base,
                                                   float* __restrict__ dstrep) {
    int id = blockIdx.x * 256 + threadIdx.x;
    if (id >= NITEM * 128) return;
    int r = id >> 7, d = id & 127;
    float acc = 0.f;
    #pragma unroll
    for (int j = 0; j < KITEM; j++) {
        int c = col[r * KITEM + j];
        acc += vals[r * KITEM + j] * srcrep[(size_t)c * 128 + d];
    }
    if (ADD_BASE) acc += base[id];
    dstrep[id] = acc;
}

extern "C" void kernel_launch(void* const* d_in, const int* in_sizes, int n_in,
                              void* d_out, int out_size, void* d_ws, size_t ws_size,
                              hipStream_t stream) {
    const int*   edge_index = (const int*)d_in[0];
    const float* v_feat   = (const float*)d_in[1];
    const float* t_feat   = (const float*)d_in[2];
    const float* v_pref   = (const float*)d_in[3];
    const float* t_pref   = (const float*)d_in[4];
    const float* v_mlp1_w = (const float*)d_in[5];
    const float* v_mlp1_b = (const float*)d_in[6];
    const float* v_mlp2_w = (const float*)d_in[7];
    const float* v_mlp2_b = (const float*)d_in[8];
    const float* t_mlp1_w = (const float*)d_in[9];
    const float* t_mlp1_b = (const float*)d_in[10];
    const float* t_mlp2_w = (const float*)d_in[11];
    const float* t_mlp2_b = (const float*)d_in[12];
    const float* v_conv_w = (const float*)d_in[13];
    const float* v_conv_b = (const float*)d_in[14];
    const float* t_conv_w = (const float*)d_in[15];
    const float* t_conv_b = (const float*)d_in[16];
    const float* weight_u = (const float*)d_in[17];
    const int*   user_graph = (const int*)d_in[18];
    const float* uwm      = (const float*)d_in[19];
    const int*   mm_indices = (const int*)d_in[20];
    const float* mm_values  = (const float*)d_in[21];
    float* out = (float*)d_out;

    char* wsb = (char*)d_ws;
    size_t off = 0;
    auto alloc = [&](size_t bytes) -> void* {
        void* p = wsb + off;
        off = (off + bytes + 255) & ~(size_t)255;
        return p;
    };
    int*   cnt     = (int*)  alloc(NNODE * 4);          // later reused as CSR fill cursor
    float* dinv    = (float*)alloc(NNODE * 4);
    int*   rowptr  = (int*)  alloc((NNODE + 1) * 4);
    int*   bsum    = (int*)  alloc(256 * 4);
    int*   csr_src = (int*)  alloc((size_t)2 * NE * 4);
    short* Btw     = (short*)alloc((size_t)256 * 2048 * 2);
    float* mid     = (float*)alloc((size_t)NITEM * 256 * 4);
    float* x       = (float*)alloc((size_t)NNODE * DIM * 4);
    float* h       = (float*)alloc((size_t)NNODE * DIM * 4);
    float* h1      = (float*)alloc((size_t)NNODE * DIM * 4);
    float* gw      = (float*)alloc((size_t)NNODE * DIM * 4);
    float* rep0    = (float*)alloc((size_t)NNODE * 128 * 4);
    (void)ws_size; (void)n_in; (void)in_sizes; (void)out_size;

    const int* e_src = edge_index;
    const int* e_dst = edge_index + 2 * NE;
    const int* mm_col = mm_indices + NITEM * KITEM;

    const int NB = (NNODE + 255) / 256;   // 235

    // degree + dinv
    hipMemsetAsync(cnt, 0, NNODE * 4, stream);
    k_count<<<(2 * NE + 255) / 256, 256, 0, stream>>>(e_dst, cnt, 2 * NE);
    k_dinv<<<(NNODE + 255) / 256, 256, 0, stream>>>(cnt, dinv);

    // CSR build: exclusive scan of cnt -> rowptr, then atomic-cursor fill
    k_scanA<<<NB, 256, 0, stream>>>(cnt, rowptr, bsum, NNODE);
    k_scanB<<<1, 256, 0, stream>>>(bsum, NB);
    k_scanC<<<NB, 256, 0, stream>>>(rowptr, bsum, NNODE);
    k_copy_int<<<NB, 256, 0, stream>>>(rowptr, cnt, NNODE);   // cursor = cnt buffer
    k_fill<<<(2 * NE + 255) / 256, 256, 0, stream>>>(e_src, e_dst, cnt, csr_src, 2 * NE);

    auto run_branch = [&](const float* feat, int featK, const float* pref,
                          const float* w1, const float* b1, const float* w2, const float* b2,
                          const float* cw, const float* cb, int colOff, int wIdx) {
        // MLP1 via MFMA: mid = lrelu(feat @ w1 + b1)
        {
            dim3 tg(featK / 16, 16);
            k_transpose_bf16<<<tg, 256, 0, stream>>>(w1, Btw, featK);
            mfma_mlp1<<<(NITEM + 63) / 64, 256, 0, stream>>>(feat, Btw, b1, mid, NITEM, featK);
        }
        // MLP2: x rows NUSER.. = mid @ w2 + b2
        {
            dim3 g(1, (NITEM + 63) / 64);
            sgemm<false, true><<<g, 256, 0, stream>>>(mid, w2, b2, x + (size_t)NUSER * DIM, NITEM, DIM, 256);
        }
        k_copy4<<<(NUSER * DIM / 4 + 255) / 256, 256, 0, stream>>>((const float4*)pref, (float4*)x, NUSER * DIM / 4);
        k_l2n<<<(NNODE + 3) / 4, 256, 0, stream>>>(x);
        // conv1
        {
            dim3 g(1, (NNODE + 63) / 64);
            sgemm<false, false><<<g, 256, 0, stream>>>(x, cw, nullptr, gw, NNODE, DIM, DIM);
        }
        k_gather<<<(NNODE + 3) / 4, 256, 0, stream>>>(rowptr, csr_src, dinv, gw, cb, h);
        // conv2
        {
            dim3 g(1, (NNODE + 63) / 64);
            sgemm<false, false><<<g, 256, 0, stream>>>(h, cw, nullptr, gw, NNODE, DIM, DIM);
        }
        k_gather<<<(NNODE + 3) / 4, 256, 0, stream>>>(rowptr, csr_src, dinv, gw, cb, h1);
        k_accum_rep<<<(NNODE * DIM + 255) / 256, 256, 0, stream>>>(x, h, h1, weight_u, rep0, colOff, wIdx);
    };

    run_branch(v_feat, 2048, v_pref, v_mlp1_w, v_mlp1_b, v_mlp2_w, v_mlp2_b, v_conv_w, v_conv_b, 0, 0);
    run_branch(t_feat, 768,  t_pref, t_mlp1_w, t_mlp1_b, t_mlp2_w, t_mlp2_b, t_conv_w, t_conv_b, 64, 1);

    k_user<<<(NUSER * 128 + 255) / 256, 256, 0, stream>>>(rep0, user_graph, uwm, out);

    const float* item0 = rep0 + (size_t)NUSER * 128;
    k_item_prop<false><<<(NITEM * 128 + 255) / 256, 256, 0, stream>>>(item0, mm_col, mm_values, nullptr, mid);
    k_item_prop<true><<<(NITEM * 128 + 255) / 256, 256, 0, stream>>>(mid, mm_col, mm_values, item0, out + (size_t)NUSER * 128);
}

// Round 4
// 953.141 us; speedup vs baseline: 3.4498x; 1.2163x over previous
//
#include <hip/hip_runtime.h>

#define NUSER 20000
#define NITEM 40000
#define NNODE 60000
#define DIM   64
#define NE    1000000   // per direction; total directed edges = 2*NE
#define KUSER 40
#define KITEM 10

typedef __attribute__((ext_vector_type(8))) short short8v;
typedef __attribute__((ext_vector_type(4))) float floatx4;
typedef __attribute__((ext_vector_type(4))) unsigned short ushort4v;

__device__ inline short bf16rne(float f) {
    unsigned u = __builtin_bit_cast(unsigned, f);
    unsigned r = (u + 0x7fffu + ((u >> 16) & 1u)) >> 16;
    return (short)r;
}
__device__ inline float bflo(unsigned v) { return __builtin_bit_cast(float, v << 16); }
__device__ inline float bfhi(unsigned v) { return __builtin_bit_cast(float, v & 0xffff0000u); }

// ---------------- degree / norm ----------------
__global__ __launch_bounds__(256) void k_count(const int* __restrict__ dst, int* __restrict__ cnt, int n) {
    int i = blockIdx.x * 256 + threadIdx.x;
    if (i < n) atomicAdd(&cnt[dst[i]], 1);
}

__global__ __launch_bounds__(256) void k_dinv(const int* __restrict__ cnt, float* __restrict__ dinv) {
    int i = blockIdx.x * 256 + threadIdx.x;
    if (i < NNODE) dinv[i] = 1.0f / sqrtf((float)(cnt[i] + 1));  // +1 self loop
}

// ---------------- exclusive scan (3-kernel) ----------------
__global__ __launch_bounds__(256) void k_scanA(const int* __restrict__ v, int* __restrict__ excl,
                                               int* __restrict__ bsum, int n) {
    __shared__ int s[256];
    int t = threadIdx.x, i = blockIdx.x * 256 + t;
    int orig = (i < n) ? v[i] : 0;
    s[t] = orig; __syncthreads();
    #pragma unroll
    for (int off = 1; off < 256; off <<= 1) {
        int u = (t >= off) ? s[t - off] : 0;
        __syncthreads();
        s[t] += u;
        __syncthreads();
    }
    if (i < n) excl[i] = s[t] - orig;
    if (t == 255) bsum[blockIdx.x] = s[255];
}

__global__ __launch_bounds__(256) void k_scanB(int* __restrict__ bsum, int nb) {
    __shared__ int s[256];
    int t = threadIdx.x;
    int orig = (t < nb) ? bsum[t] : 0;
    s[t] = orig; __syncthreads();
    #pragma unroll
    for (int off = 1; off < 256; off <<= 1) {
        int u = (t >= off) ? s[t - off] : 0;
        __syncthreads();
        s[t] += u;
        __syncthreads();
    }
    if (t < nb) bsum[t] = s[t] - orig;  // exclusive
}

__global__ __launch_bounds__(256) void k_scanC(int* __restrict__ excl, const int* __restrict__ bsum, int n) {
    int i = blockIdx.x * 256 + threadIdx.x;
    if (i < n) excl[i] += bsum[blockIdx.x];
    if (i == 0) excl[n] = 2 * NE;
}

__global__ __launch_bounds__(256) void k_copy_int(const int* __restrict__ s, int* __restrict__ d, int n) {
    int i = blockIdx.x * 256 + threadIdx.x;
    if (i < n) d[i] = s[i];
}

__global__ __launch_bounds__(256) void k_fill(const int* __restrict__ src, const int* __restrict__ dst,
                                              int* __restrict__ cursor, int* __restrict__ csr_src, int n) {
    int i = blockIdx.x * 256 + threadIdx.x;
    if (i >= n) return;
    int d = dst[i];
    int pos = atomicAdd(&cursor[d], 1);
    csr_src[pos] = src[i];
}

// ---------------- weight transpose + bf16 cast, k-blocked: Btb[k/32][n][k%32] ----------------
__global__ __launch_bounds__(256) void k_transpose_bf16(const float* __restrict__ B, short* __restrict__ Btb, int K) {
    __shared__ float s[16][17];
    int t = threadIdx.x, tx = t & 15, ty = t >> 4;
    int k0 = blockIdx.x * 16, n0 = blockIdx.y * 16;
    s[ty][tx] = B[(size_t)(k0 + ty) * 256 + n0 + tx];
    __syncthreads();
    int k = k0 + tx, n = n0 + ty;
    Btb[(size_t)(k >> 5) * 8192 + n * 32 + (k & 31)] = bf16rne(s[tx][ty]);
}

// ---------------- MFMA MLP1: C = lrelu(A @ B + bias) ----------------
// A: MxK f32.  Btb: k-blocked bf16 [K/32][256][32].  C: Mx256 f32.
#define APAD 36
__global__ __launch_bounds__(256) void mfma_mlp1(const float* __restrict__ A, const short* __restrict__ Btb,
                                                 const float* __restrict__ bias, float* __restrict__ C,
                                                 int M, int K) {
    __shared__ short As[2][64 * APAD];
    __shared__ short Bs[2][256 * APAD];
    const int tid = threadIdx.x;
    const int lane = tid & 63, wc = tid >> 6;
    const int rowBase = blockIdx.x * 64;

    const int sar = tid >> 2, sac = (tid & 3) * 8;
    int arow = rowBase + sar; if (arow >= M) arow = M - 1;
    const float* aptr = A + (size_t)arow * K + sac;

    const int fk = (lane >> 4) * 8;
    const int faoff = (lane & 15) * APAD + fk;
    const int fboff = (wc * 64 + (lane & 15)) * APAD + fk;

    floatx4 acc[4][4];
    #pragma unroll
    for (int m = 0; m < 4; m++)
        #pragma unroll
        for (int n = 0; n < 4; n++) acc[m][n] = (floatx4)0.f;

    float4 ra0, ra1;
    short8v rb[4];
    const int nk = K >> 5;

    auto ldg = [&](int ks) {
        const float* ap = aptr + ks * 32;
        ra0 = *(const float4*)(ap);
        ra1 = *(const float4*)(ap + 4);
        const short* bsrc = Btb + (size_t)ks * 8192 + tid * 8;
        #pragma unroll
        for (int it = 0; it < 4; it++) rb[it] = *(const short8v*)(bsrc + it * 2048);
    };
    auto stv = [&](int buf) {
        short8v av;
        av[0] = bf16rne(ra0.x); av[1] = bf16rne(ra0.y); av[2] = bf16rne(ra0.z); av[3] = bf16rne(ra0.w);
        av[4] = bf16rne(ra1.x); av[5] = bf16rne(ra1.y); av[6] = bf16rne(ra1.z); av[7] = bf16rne(ra1.w);
        *(short8v*)&As[buf][sar * APAD + sac] = av;
        #pragma unroll
        for (int it = 0; it < 4; it++)
            *(short8v*)&Bs[buf][(sar + it * 64) * APAD + sac] = rb[it];
    };

    ldg(0); stv(0);
    __syncthreads();
    int cur = 0;
    for (int ks = 0; ks < nk; ++ks) {
        if (ks + 1 < nk) ldg(ks + 1);
        short8v a[4], b[4];
        #pragma unroll
        for (int m = 0; m < 4; m++) a[m] = *(const short8v*)&As[cur][faoff + m * 16 * APAD];
        #pragma unroll
        for (int n = 0; n < 4; n++) b[n] = *(const short8v*)&Bs[cur][fboff + n * 16 * APAD];
        #pragma unroll
        for (int m = 0; m < 4; m++)
            #pragma unroll
            for (int n = 0; n < 4; n++)
                acc[m][n] = __builtin_amdgcn_mfma_f32_16x16x32_bf16(a[m], b[n], acc[m][n], 0, 0, 0);
        if (ks + 1 < nk) stv(cur ^ 1);
        __syncthreads();
        cur ^= 1;
    }

    const int c0 = wc * 64 + (lane & 15);
    #pragma unroll
    for (int n = 0; n < 4; n++) {
        float bn = bias[c0 + n * 16];
        #pragma unroll
        for (int m = 0; m < 4; m++) {
            int r0 = rowBase + m * 16 + (lane >> 4) * 4;
            #pragma unroll
            for (int q = 0; q < 4; q++) {
                int r = r0 + q;
                if (r < M) {
                    float v = acc[m][n][q] + bn;
                    C[(size_t)r * 256 + c0 + n * 16] = v > 0.f ? v : 0.01f * v;
                }
            }
        }
    }
}

// ---------------- tiled SGEMM with lda/ldc/colOff and optional bf16 strided out ----------------
template<bool LRELU, bool BIAS, bool BF16OUT>
__global__ __launch_bounds__(256) void sgemm(const float* __restrict__ A, const float* __restrict__ B,
                                             const float* __restrict__ bias, float* __restrict__ Cf,
                                             unsigned short* __restrict__ Ch,
                                             int M, int N, int K, int lda, int ldc, int colOff) {
    __shared__ float As[16][65];
    __shared__ float Bs[16][65];
    const int tid = threadIdx.x;
    const int tx = tid & 15, ty = tid >> 4;
    const int rowBase = blockIdx.y * 64, colBase = blockIdx.x * 64;
    float acc[4][4] = {};
    for (int k0 = 0; k0 < K; k0 += 16) {
        {
            int r = tid >> 2, c = (tid & 3) * 4;
            int gr = rowBase + r;
            float4 v = make_float4(0.f, 0.f, 0.f, 0.f);
            if (gr < M) v = *(const float4*)(A + (size_t)gr * lda + k0 + c);
            As[c + 0][r] = v.x; As[c + 1][r] = v.y; As[c + 2][r] = v.z; As[c + 3][r] = v.w;
        }
        {
            int r = tid >> 4, c = (tid & 15) * 4;
            float4 v = *(const float4*)(B + (size_t)(k0 + r) * N + colBase + c);
            Bs[r][c + 0] = v.x; Bs[r][c + 1] = v.y; Bs[r][c + 2] = v.z; Bs[r][c + 3] = v.w;
        }
        __syncthreads();
        #pragma unroll
        for (int k = 0; k < 16; k++) {
            float a[4], b[4];
            #pragma unroll
            for (int i = 0; i < 4; i++) a[i] = As[k][ty * 4 + i];
            #pragma unroll
            for (int j = 0; j < 4; j++) b[j] = Bs[k][tx * 4 + j];
            #pragma unroll
            for (int i = 0; i < 4; i++)
                #pragma unroll
                for (int j = 0; j < 4; j++) acc[i][j] += a[i] * b[j];
        }
        __syncthreads();
    }
    const int gr0 = rowBase + ty * 4, gc = colBase + tx * 4;
    #pragma unroll
    for (int i = 0; i < 4; i++) {
        if (gr0 + i >= M) break;
        float s[4];
        #pragma unroll
        for (int j = 0; j < 4; j++) {
            float v = acc[i][j];
            if (BIAS) v += bias[gc + j];
            if (LRELU) v = v > 0.f ? v : 0.01f * v;
            s[j] = v;
        }
        if (BF16OUT) {
            ushort4v h;
            #pragma unroll
            for (int j = 0; j < 4; j++) h[j] = (unsigned short)bf16rne(s[j]);
            *(ushort4v*)(Ch + (size_t)(gr0 + i) * ldc + colOff + gc) = h;
        } else {
            float4 v = make_float4(s[0], s[1], s[2], s[3]);
            *(float4*)(Cf + (size_t)(gr0 + i) * ldc + colOff + gc) = v;
        }
    }
}

// ---------------- misc ----------------
__global__ __launch_bounds__(256) void k_copy4(const float4* __restrict__ s, float4* __restrict__ d, int n4) {
    int i = blockIdx.x * 256 + threadIdx.x;
    if (i < n4) d[i] = s[i];
}

__global__ __launch_bounds__(256) void k_l2n(float* __restrict__ x) {
    int row = blockIdx.x * 4 + (threadIdx.x >> 6);
    int lane = threadIdx.x & 63;
    if (row >= NNODE) return;
    float v = x[(size_t)row * 64 + lane];
    float ss = v * v;
    #pragma unroll
    for (int off = 32; off >= 1; off >>= 1) ss += __shfl_xor(ss, off, 64);
    float n = fmaxf(sqrtf(ss), 1e-12f);
    x[(size_t)row * 64 + lane] = v / n;
}

// fused dual-branch CSR gather over bf16 gw2[NNODE][128] (uint-packed pairs).
// h2[row][c] = cb(c) + dinv[row]*(dinv[row]*gw2[row][c] + sum_e dinv[s_e]*gw2[s_e][c])
__global__ __launch_bounds__(256) void k_gather2(const int* __restrict__ rowptr, const int* __restrict__ csr_src,
                                                 const float* __restrict__ dinv, const unsigned* __restrict__ gw2,
                                                 const float* __restrict__ cbv, const float* __restrict__ cbt,
                                                 float* __restrict__ h2) {
    int row = blockIdx.x * 4 + (threadIdx.x >> 6);
    int lane = threadIdx.x & 63;
    if (row >= NNODE) return;
    int p0 = rowptr[row], p1 = rowptr[row + 1];
    float dr = dinv[row];
    unsigned sv = gw2[(size_t)row * 64 + lane];
    float2 acc;
    acc.x = dr * bflo(sv);
    acc.y = dr * bfhi(sv);
    for (int p = p0; p < p1; p += 64) {
        int c = p1 - p; if (c > 64) c = 64;
        int s = (lane < c) ? csr_src[p + lane] : 0;
        float w = (lane < c) ? dinv[s] : 0.f;
        #pragma unroll 4
        for (int j = 0; j < c; ++j) {
            int sj = __shfl(s, j, 64);
            float wj = __shfl(w, j, 64);
            unsigned v = gw2[(size_t)sj * 64 + lane];
            acc.x += wj * bflo(v);
            acc.y += wj * bfhi(v);
        }
    }
    int c0 = 2 * lane;
    float b0 = (c0 < 64) ? cbv[c0] : cbt[c0 - 64];
    float b1 = (c0 + 1 < 64) ? cbv[c0 + 1] : cbt[c0 + 1 - 64];
    float2 r;
    r.x = b0 + dr * acc.x;
    r.y = b1 + dr * acc.y;
    *(float2*)(h2 + (size_t)row * 128 + c0) = r;
}

// rep0[row][colOff+c] = (row<NUSER ? weight_u[row*2+wIdx] : 1) * (x + h2 + h12)
__global__ __launch_bounds__(256) void k_accum_rep(const float* __restrict__ x, const float* __restrict__ h2,
                                                   const float* __restrict__ h12, const float* __restrict__ weight_u,
                                                   float* __restrict__ rep0, int colOff, int wIdx) {
    int id = blockIdx.x * 256 + threadIdx.x;
    if (id >= NNODE * DIM) return;
    int row = id >> 6, c = id & 63;
    float s = x[id] + h2[(size_t)row * 128 + colOff + c] + h12[(size_t)row * 128 + colOff + c];
    float w = (row < NUSER) ? weight_u[row * 2 + wIdx] : 1.0f;
    rep0[(size_t)row * 128 + colOff + c] = w * s;
}

__global__ __launch_bounds__(256) void k_user(const float* __restrict__ rep0, const int* __restrict__ ug,
                                              const float* __restrict__ uwm, float* __restrict__ out) {
    int id = blockIdx.x * 256 + threadIdx.x;
    if (id >= NUSER * 128) return;
    int u = id >> 7, d = id & 127;
    float acc = rep0[id];
    #pragma unroll 4
    for (int k = 0; k < KUSER; k++) {
        int nb = ug[u * KUSER + k];
        acc += uwm[u * KUSER + k] * rep0[(size_t)nb * 128 + d];
    }
    out[id] = acc;
}

template<bool ADD_BASE>
__global__ __launch_bounds__(256) void k_item_prop(const float* __restrict__ srcrep, const int* __restrict__ col,
                                                   const float* __restrict__ vals, const float* __restrict__ base,
                                                   float* __restrict__ dstrep) {
    int id = blockIdx.x * 256 + threadIdx.x;
    if (id >= NITEM * 128) return;
    int r = id >> 7, d = id & 127;
    float acc = 0.f;
    #pragma unroll
    for (int j = 0; j < KITEM; j++) {
        int c = col[r * KITEM + j];
        acc += vals[r * KITEM + j] * srcrep[(size_t)c * 128 + d];
    }
    if (ADD_BASE) acc += base[id];
    dstrep[id] = acc;
}

extern "C" void kernel_launch(void* const* d_in, const int* in_sizes, int n_in,
                              void* d_out, int out_size, void* d_ws, size_t ws_size,
                              hipStream_t stream) {
    const int*   edge_index = (const int*)d_in[0];
    const float* v_feat   = (const float*)d_in[1];
    const float* t_feat   = (const float*)d_in[2];
    const float* v_pref   = (const float*)d_in[3];
    const float* t_pref   = (const float*)d_in[4];
    const float* v_mlp1_w = (const float*)d_in[5];
    const float* v_mlp1_b = (const float*)d_in[6];
    const float* v_mlp2_w = (const float*)d_in[7];
    const float* v_mlp2_b = (const float*)d_in[8];
    const float* t_mlp1_w = (const float*)d_in[9];
    const float* t_mlp1_b = (const float*)d_in[10];
    const float* t_mlp2_w = (const float*)d_in[11];
    const float* t_mlp2_b = (const float*)d_in[12];
    const float* v_conv_w = (const float*)d_in[13];
    const float* v_conv_b = (const float*)d_in[14];
    const float* t_conv_w = (const float*)d_in[15];
    const float* t_conv_b = (const float*)d_in[16];
    const float* weight_u = (const float*)d_in[17];
    const int*   user_graph = (const int*)d_in[18];
    const float* uwm      = (const float*)d_in[19];
    const int*   mm_indices = (const int*)d_in[20];
    const float* mm_values  = (const float*)d_in[21];
    float* out = (float*)d_out;

    char* wsb = (char*)d_ws;
    size_t off = 0;
    auto alloc = [&](size_t bytes) -> void* {
        void* p = wsb + off;
        off = (off + bytes + 255) & ~(size_t)255;
        return p;
    };
    int*   cnt     = (int*)  alloc(NNODE * 4);
    float* dinv    = (float*)alloc(NNODE * 4);
    int*   rowptr  = (int*)  alloc((NNODE + 1) * 4);
    int*   bsum    = (int*)  alloc(256 * 4);
    int*   csr_src = (int*)  alloc((size_t)2 * NE * 4);
    short* Btw     = (short*)alloc((size_t)256 * 2048 * 2);
    float* mid     = (float*)alloc((size_t)NITEM * 256 * 4);
    float* xv      = (float*)alloc((size_t)NNODE * DIM * 4);
    float* xt      = (float*)alloc((size_t)NNODE * DIM * 4);
    unsigned short* gw2 = (unsigned short*)alloc((size_t)NNODE * 128 * 2);
    float* h2      = (float*)alloc((size_t)NNODE * 128 * 4);
    float* h12     = (float*)alloc((size_t)NNODE * 128 * 4);
    float* rep0    = (float*)alloc((size_t)NNODE * 128 * 4);
    (void)ws_size; (void)n_in; (void)in_sizes; (void)out_size;

    const int* e_src = edge_index;
    const int* e_dst = edge_index + 2 * NE;
    const int* mm_col = mm_indices + NITEM * KITEM;

    const int NB = (NNODE + 255) / 256;   // 235

    // degree + dinv + CSR
    hipMemsetAsync(cnt, 0, NNODE * 4, stream);
    k_count<<<(2 * NE + 255) / 256, 256, 0, stream>>>(e_dst, cnt, 2 * NE);
    k_dinv<<<(NNODE + 255) / 256, 256, 0, stream>>>(cnt, dinv);
    k_scanA<<<NB, 256, 0, stream>>>(cnt, rowptr, bsum, NNODE);
    k_scanB<<<1, 256, 0, stream>>>(bsum, NB);
    k_scanC<<<NB, 256, 0, stream>>>(rowptr, bsum, NNODE);
    k_copy_int<<<NB, 256, 0, stream>>>(rowptr, cnt, NNODE);
    k_fill<<<(2 * NE + 255) / 256, 256, 0, stream>>>(e_src, e_dst, cnt, csr_src, 2 * NE);

    // per-branch MLP -> x (L2-normalized)
    auto run_mlp = [&](const float* feat, int featK, const float* pref,
                       const float* w1, const float* b1, const float* w2, const float* b2, float* x) {
        dim3 tg(featK / 16, 16);
        k_transpose_bf16<<<tg, 256, 0, stream>>>(w1, Btw, featK);
        mfma_mlp1<<<(NITEM + 63) / 64, 256, 0, stream>>>(feat, Btw, b1, mid, NITEM, featK);
        dim3 g(1, (NITEM + 63) / 64);
        sgemm<false, true, false><<<g, 256, 0, stream>>>(mid, w2, b2, x + (size_t)NUSER * DIM, nullptr,
                                                         NITEM, DIM, 256, 256, DIM, 0);
        k_copy4<<<(NUSER * DIM / 4 + 255) / 256, 256, 0, stream>>>((const float4*)pref, (float4*)x, NUSER * DIM / 4);
        k_l2n<<<(NNODE + 3) / 4, 256, 0, stream>>>(x);
    };
    run_mlp(v_feat, 2048, v_pref, v_mlp1_w, v_mlp1_b, v_mlp2_w, v_mlp2_b, xv);
    run_mlp(t_feat, 768,  t_pref, t_mlp1_w, t_mlp1_b, t_mlp2_w, t_mlp2_b, xt);

    dim3 gc(1, (NNODE + 63) / 64);
    // conv1: gw2[:,0:64] = bf16(xv @ v_conv_w), gw2[:,64:128] = bf16(xt @ t_conv_w)
    sgemm<false, false, true><<<gc, 256, 0, stream>>>(xv, v_conv_w, nullptr, nullptr, gw2, NNODE, DIM, DIM, DIM, 128, 0);
    sgemm<false, false, true><<<gc, 256, 0, stream>>>(xt, t_conv_w, nullptr, nullptr, gw2, NNODE, DIM, DIM, DIM, 128, 64);
    k_gather2<<<(NNODE + 3) / 4, 256, 0, stream>>>(rowptr, csr_src, dinv, (const unsigned*)gw2, v_conv_b, t_conv_b, h2);
    // conv2: gw2 = bf16(h2[:,branch] @ conv_w)
    sgemm<false, false, true><<<gc, 256, 0, stream>>>(h2,      v_conv_w, nullptr, nullptr, gw2, NNODE, DIM, DIM, 128, 128, 0);
    sgemm<false, false, true><<<gc, 256, 0, stream>>>(h2 + 64, t_conv_w, nullptr, nullptr, gw2, NNODE, DIM, DIM, 128, 128, 64);
    k_gather2<<<(NNODE + 3) / 4, 256, 0, stream>>>(rowptr, csr_src, dinv, (const unsigned*)gw2, v_conv_b, t_conv_b, h12);

    // rep0 = weighted (x + h + h1), both branches
    k_accum_rep<<<(NNODE * DIM + 255) / 256, 256, 0, stream>>>(xv, h2, h12, weight_u, rep0, 0, 0);
    k_accum_rep<<<(NNODE * DIM + 255) / 256, 256, 0, stream>>>(xt, h2, h12, weight_u, rep0, 64, 1);

    // users
    k_user<<<(NUSER * 128 + 255) / 256, 256, 0, stream>>>(rep0, user_graph, uwm, out);

    // items: 2-layer item-item propagation (reuse mid as intermediate)
    const float* item0 = rep0 + (size_t)NUSER * 128;
    k_item_prop<false><<<(NITEM * 128 + 255) / 256, 256, 0, stream>>>(item0, mm_col, mm_values, nullptr, mid);
    k_item_prop<true><<<(NITEM * 128 + 255) / 256, 256, 0, stream>>>(mid, mm_col, mm_values, item0, out + (size_t)NUSER * 128);
}

// Round 5
// 661.766 us; speedup vs baseline: 4.9688x; 1.4403x over previous
//
#include <hip/hip_runtime.h>

#define NUSER 20000
#define NITEM 40000
#define NNODE 60000
#define DIM   64
#define NE    1000000   // per direction; total directed edges = 2*NE
#define KUSER 40
#define KITEM 10

typedef __attribute__((ext_vector_type(8))) short short8v;
typedef __attribute__((ext_vector_type(4))) float floatx4;

__device__ inline short bf16rne(float f) {
    unsigned u = __builtin_bit_cast(unsigned, f);
    unsigned r = (u + 0x7fffu + ((u >> 16) & 1u)) >> 16;
    return (short)r;
}
__device__ inline unsigned cvt_pk_bf16(float lo, float hi) {   // dst.lo16=bf16(lo), dst.hi16=bf16(hi)
    unsigned r;
    asm("v_cvt_pk_bf16_f32 %0, %1, %2" : "=v"(r) : "v"(lo), "v"(hi));
    return r;
}
__device__ inline float bflo(unsigned v) { return __builtin_bit_cast(float, v << 16); }
__device__ inline float bfhi(unsigned v) { return __builtin_bit_cast(float, v & 0xffff0000u); }

// ---------------- degree / norm ----------------
__global__ __launch_bounds__(256) void k_count(const int* __restrict__ dst, int* __restrict__ cnt, int n) {
    int i = blockIdx.x * 256 + threadIdx.x;
    if (i < n) atomicAdd(&cnt[dst[i]], 1);
}

__global__ __launch_bounds__(256) void k_dinv(const int* __restrict__ cnt, float* __restrict__ dinv) {
    int i = blockIdx.x * 256 + threadIdx.x;
    if (i < NNODE) dinv[i] = 1.0f / sqrtf((float)(cnt[i] + 1));  // +1 self loop
}

// ---------------- exclusive scan (3-kernel) ----------------
__global__ __launch_bounds__(256) void k_scanA(const int* __restrict__ v, int* __restrict__ excl,
                                               int* __restrict__ bsum, int n) {
    __shared__ int s[256];
    int t = threadIdx.x, i = blockIdx.x * 256 + t;
    int orig = (i < n) ? v[i] : 0;
    s[t] = orig; __syncthreads();
    #pragma unroll
    for (int off = 1; off < 256; off <<= 1) {
        int u = (t >= off) ? s[t - off] : 0;
        __syncthreads();
        s[t] += u;
        __syncthreads();
    }
    if (i < n) excl[i] = s[t] - orig;
    if (t == 255) bsum[blockIdx.x] = s[255];
}

__global__ __launch_bounds__(256) void k_scanB(int* __restrict__ bsum, int nb) {
    __shared__ int s[256];
    int t = threadIdx.x;
    int orig = (t < nb) ? bsum[t] : 0;
    s[t] = orig; __syncthreads();
    #pragma unroll
    for (int off = 1; off < 256; off <<= 1) {
        int u = (t >= off) ? s[t - off] : 0;
        __syncthreads();
        s[t] += u;
        __syncthreads();
    }
    if (t < nb) bsum[t] = s[t] - orig;  // exclusive
}

__global__ __launch_bounds__(256) void k_scanC(int* __restrict__ excl, const int* __restrict__ bsum,
                                               int* __restrict__ cursor, int n) {
    int i = blockIdx.x * 256 + threadIdx.x;
    if (i < n) {
        int v = excl[i] + bsum[blockIdx.x];
        excl[i] = v;
        cursor[i] = v;
    }
    if (i == 0) excl[n] = 2 * NE;
}

// fill packed CSR: entry = (bf16bits(dinv[src]) << 16) | src   (src < 65536)
__global__ __launch_bounds__(256) void k_fill(const int* __restrict__ src, const int* __restrict__ dst,
                                              const float* __restrict__ dinv, int* __restrict__ cursor,
                                              unsigned* __restrict__ csr_pkd, int n) {
    int i = blockIdx.x * 256 + threadIdx.x;
    if (i >= n) return;
    int s = src[i], d = dst[i];
    unsigned pk = ((unsigned)(unsigned short)bf16rne(dinv[s]) << 16) | (unsigned)s;
    int pos = atomicAdd(&cursor[d], 1);
    csr_pkd[pos] = pk;
}

// ---------------- weight transpose + bf16 cast, k-blocked: Btb[k/32][n][k%32] ----------------
__global__ __launch_bounds__(256) void k_transpose_bf16(const float* __restrict__ B, short* __restrict__ Btb,
                                                        int K, int N) {
    __shared__ float s[16][17];
    int t = threadIdx.x, tx = t & 15, ty = t >> 4;
    int k0 = blockIdx.x * 16, n0 = blockIdx.y * 16;
    s[ty][tx] = B[(size_t)(k0 + ty) * N + n0 + tx];
    __syncthreads();
    int k = k0 + tx, n = n0 + ty;
    Btb[(size_t)(k >> 5) * (N * 32) + n * 32 + (k & 31)] = bf16rne(s[tx][ty]);
}

// ---------------- fused MLP: X = l2n(lrelu(A@W1+b1)@W2+b2), MFMA both GEMMs ----------------
// A: Mx K f32 (M = NITEM, divisible by 64). B1t: [K/32][256][32] bf16. B2t: [8][64][32] bf16.
// Block = 64 rows, 4 waves. Phase1: 64x256 in acc. Phase2: mid bf16 -> LDS (reuse Bs).
// Phase3: 64x64 temp via MFMA. Phase4: in-register row L2-norm, write X.
#define AP   40    // LDS row pad (80B, 16B-aligned, 2-way bank alias = free)
#define MIDP 264   // mid row pad (528B, 16B-aligned)
__global__ __launch_bounds__(256) void mlp_fused(const float* __restrict__ A, const short* __restrict__ B1t,
                                                 const float* __restrict__ b1, const short* __restrict__ B2t,
                                                 const float* __restrict__ b2, float* __restrict__ X, int K) {
    __shared__ short smem[2 * 64 * AP + 2 * 256 * AP];
    short* As = smem;                 // [2][64*AP]
    short* Bs = smem + 2 * 64 * AP;   // [2][256*AP]; reused as mid[64][MIDP]
    const int tid = threadIdx.x;
    const int lane = tid & 63, wid = tid >> 6;
    const int rowBase = blockIdx.x * 64;

    const int sar = tid >> 2, sac = (tid & 3) * 8;
    const float* aptr = A + (size_t)(rowBase + sar) * K + sac;

    const int fk = (lane >> 4) * 8;
    const int faoff = (lane & 15) * AP + fk;
    const int fboff = (wid * 64 + (lane & 15)) * AP + fk;

    floatx4 acc[4][4];
    #pragma unroll
    for (int m = 0; m < 4; m++)
        #pragma unroll
        for (int n = 0; n < 4; n++) acc[m][n] = (floatx4)0.f;

    float4 ra0, ra1;
    short8v rb[4];
    const int nk = K >> 5;

    auto ldg = [&](int ks) {
        const float* ap = aptr + ks * 32;
        ra0 = *(const float4*)(ap);
        ra1 = *(const float4*)(ap + 4);
        const short* bsrc = B1t + (size_t)ks * 8192 + tid * 8;
        #pragma unroll
        for (int it = 0; it < 4; it++) rb[it] = *(const short8v*)(bsrc + it * 2048);
    };
    auto stv = [&](int buf) {
        uint4 av;
        av.x = cvt_pk_bf16(ra0.x, ra0.y); av.y = cvt_pk_bf16(ra0.z, ra0.w);
        av.z = cvt_pk_bf16(ra1.x, ra1.y); av.w = cvt_pk_bf16(ra1.z, ra1.w);
        *(uint4*)&As[buf * (64 * AP) + sar * AP + sac] = av;
        #pragma unroll
        for (int it = 0; it < 4; it++)
            *(short8v*)&Bs[buf * (256 * AP) + (sar + it * 64) * AP + sac] = rb[it];
    };

    ldg(0); stv(0);
    __syncthreads();
    int cur = 0;
    for (int ks = 0; ks < nk; ++ks) {
        if (ks + 1 < nk) ldg(ks + 1);
        short8v a[4], b[4];
        #pragma unroll
        for (int m = 0; m < 4; m++) a[m] = *(const short8v*)&As[cur * (64 * AP) + faoff + m * 16 * AP];
        #pragma unroll
        for (int n = 0; n < 4; n++) b[n] = *(const short8v*)&Bs[cur * (256 * AP) + fboff + n * 16 * AP];
        #pragma unroll
        for (int m = 0; m < 4; m++)
            #pragma unroll
            for (int n = 0; n < 4; n++)
                acc[m][n] = __builtin_amdgcn_mfma_f32_16x16x32_bf16(a[m], b[n], acc[m][n], 0, 0, 0);
        if (ks + 1 < nk) stv(cur ^ 1);
        __syncthreads();
        cur ^= 1;
    }

    // phase 2: bias + lrelu -> bf16 mid in LDS (C/D layout: col=lane&15, row=(lane>>4)*4+q)
    short* mid = Bs;
    float bcol[4];
    #pragma unroll
    for (int n = 0; n < 4; n++) bcol[n] = b1[wid * 64 + n * 16 + (lane & 15)];
    #pragma unroll
    for (int m = 0; m < 4; m++)
        #pragma unroll
        for (int n = 0; n < 4; n++)
            #pragma unroll
            for (int q = 0; q < 4; q++) {
                int row = m * 16 + (lane >> 4) * 4 + q;
                int col = wid * 64 + n * 16 + (lane & 15);
                float v = acc[m][n][q] + bcol[n];
                v = v > 0.f ? v : 0.01f * v;
                mid[row * MIDP + col] = bf16rne(v);
            }
    __syncthreads();

    // phase 3: temp = mid @ W2 (wave wid owns rows wid*16..wid*16+15)
    floatx4 acc2[4];
    #pragma unroll
    for (int n2 = 0; n2 < 4; n2++) acc2[n2] = (floatx4)0.f;
    const int arow = wid * 16 + (lane & 15);
    #pragma unroll
    for (int ks2 = 0; ks2 < 8; ++ks2) {
        short8v af = *(const short8v*)&mid[arow * MIDP + ks2 * 32 + fk];
        const short* bp = B2t + ks2 * 2048 + fk;
        short8v bf4[4];
        #pragma unroll
        for (int n2 = 0; n2 < 4; n2++) bf4[n2] = *(const short8v*)(bp + (n2 * 16 + (lane & 15)) * 32);
        #pragma unroll
        for (int n2 = 0; n2 < 4; n2++)
            acc2[n2] = __builtin_amdgcn_mfma_f32_16x16x32_bf16(af, bf4[n2], acc2[n2], 0, 0, 0);
    }

    // phase 4: bias + row-L2-norm in-register, write X
    float b2c[4];
    #pragma unroll
    for (int n2 = 0; n2 < 4; n2++) b2c[n2] = b2[n2 * 16 + (lane & 15)];
    #pragma unroll
    for (int q = 0; q < 4; ++q) {
        float v[4]; float ss = 0.f;
        #pragma unroll
        for (int n2 = 0; n2 < 4; n2++) { v[n2] = acc2[n2][q] + b2c[n2]; ss += v[n2] * v[n2]; }
        ss += __shfl_xor(ss, 1, 64);
        ss += __shfl_xor(ss, 2, 64);
        ss += __shfl_xor(ss, 4, 64);
        ss += __shfl_xor(ss, 8, 64);
        float sc = 1.f / fmaxf(sqrtf(ss), 1e-12f);
        int grow = rowBase + wid * 16 + (lane >> 4) * 4 + q;
        #pragma unroll
        for (int n2 = 0; n2 < 4; n2++)
            X[(size_t)grow * 64 + n2 * 16 + (lane & 15)] = v[n2] * sc;
    }
}

// ---------------- pref rows: copy + L2-normalize (both branches) ----------------
__global__ __launch_bounds__(256) void k_l2n_pref(const float* __restrict__ prefv, const float* __restrict__ preft,
                                                  float* __restrict__ xv, float* __restrict__ xt) {
    int row = blockIdx.x * 4 + (threadIdx.x >> 6);
    int lane = threadIdx.x & 63;
    if (row >= NUSER) return;
    const float* p = blockIdx.y ? preft : prefv;
    float* x = blockIdx.y ? xt : xv;
    float v = p[(size_t)row * 64 + lane];
    float ss = v * v;
    #pragma unroll
    for (int off = 32; off >= 1; off >>= 1) ss += __shfl_xor(ss, off, 64);
    x[(size_t)row * 64 + lane] = v / fmaxf(sqrtf(ss), 1e-12f);
}

// ---------------- dual-branch conv GEMM: Ch[row][z*64 + c] = bf16(A_z[row] @ B_z), K=N=64 ----------------
__global__ __launch_bounds__(256) void conv_dual(const float* __restrict__ A0, const float* __restrict__ A1,
                                                 int lda, const float* __restrict__ Bv, const float* __restrict__ Bt2,
                                                 unsigned short* __restrict__ Ch) {
    __shared__ float As2[16][65];
    __shared__ float Bs2[16][65];
    const float* A = blockIdx.y ? A1 : A0;
    const float* B = blockIdx.y ? Bt2 : Bv;
    const int colOff = (int)blockIdx.y * 64;
    const int tid = threadIdx.x;
    const int tx = tid & 15, ty = tid >> 4;
    const int rowBase = blockIdx.x * 64;
    float acc[4][4] = {};
    for (int k0 = 0; k0 < 64; k0 += 16) {
        {
            int r = tid >> 2, c = (tid & 3) * 4;
            int gr = rowBase + r;
            float4 v = make_float4(0.f, 0.f, 0.f, 0.f);
            if (gr < NNODE) v = *(const float4*)(A + (size_t)gr * lda + k0 + c);
            As2[c + 0][r] = v.x; As2[c + 1][r] = v.y; As2[c + 2][r] = v.z; As2[c + 3][r] = v.w;
        }
        {
            int r = tid >> 4, c = (tid & 15) * 4;
            float4 v = *(const float4*)(B + (size_t)(k0 + r) * 64 + c);
            Bs2[r][c + 0] = v.x; Bs2[r][c + 1] = v.y; Bs2[r][c + 2] = v.z; Bs2[r][c + 3] = v.w;
        }
        __syncthreads();
        #pragma unroll
        for (int k = 0; k < 16; k++) {
            float a[4], b[4];
            #pragma unroll
            for (int i = 0; i < 4; i++) a[i] = As2[k][ty * 4 + i];
            #pragma unroll
            for (int j = 0; j < 4; j++) b[j] = Bs2[k][tx * 4 + j];
            #pragma unroll
            for (int i = 0; i < 4; i++)
                #pragma unroll
                for (int j = 0; j < 4; j++) acc[i][j] += a[i] * b[j];
        }
        __syncthreads();
    }
    const int gr0 = rowBase + ty * 4, gc = tx * 4;
    #pragma unroll
    for (int i = 0; i < 4; i++) {
        if (gr0 + i >= NNODE) break;
        uint2 hh;
        hh.x = cvt_pk_bf16(acc[i][0], acc[i][1]);
        hh.y = cvt_pk_bf16(acc[i][2], acc[i][3]);
        *(uint2*)(Ch + (size_t)(gr0 + i) * 128 + colOff + gc) = hh;
    }
}

// ---------------- fused dual-branch CSR gather (packed csr, bf16 gw2) ----------------
// h2[row][c] = cb(c) + dr*(dr*gw2[row][c] + sum_e w_e*gw2[s_e][c]),  w_e = bf16(dinv[s_e])
__global__ __launch_bounds__(256) void k_gather2(const int* __restrict__ rowptr, const unsigned* __restrict__ csr_pkd,
                                                 const float* __restrict__ dinv, const unsigned* __restrict__ gw2,
                                                 const float* __restrict__ cbv, const float* __restrict__ cbt,
                                                 float* __restrict__ h2) {
    int row = blockIdx.x * 4 + (threadIdx.x >> 6);
    int lane = threadIdx.x & 63;
    if (row >= NNODE) return;
    int p0 = rowptr[row], p1 = rowptr[row + 1];
    float dr = dinv[row];
    unsigned sv = gw2[(size_t)row * 64 + lane];
    float ax0 = dr * bflo(sv), ay0 = dr * bfhi(sv);
    float ax1 = 0.f, ay1 = 0.f;
    for (int p = p0; p < p1; p += 64) {
        int c = p1 - p; if (c > 64) c = 64;
        unsigned pk = (lane < c) ? csr_pkd[p + lane] : 0u;
        int j = 0;
        for (; j + 4 <= c; j += 4) {
            unsigned e0 = __shfl(pk, j, 64),     e1 = __shfl(pk, j + 1, 64);
            unsigned e2 = __shfl(pk, j + 2, 64), e3 = __shfl(pk, j + 3, 64);
            unsigned v0 = gw2[(size_t)(e0 & 0xffffu) * 64 + lane];
            unsigned v1 = gw2[(size_t)(e1 & 0xffffu) * 64 + lane];
            unsigned v2 = gw2[(size_t)(e2 & 0xffffu) * 64 + lane];
            unsigned v3 = gw2[(size_t)(e3 & 0xffffu) * 64 + lane];
            float w0 = bfhi(e0), w1 = bfhi(e1), w2 = bfhi(e2), w3 = bfhi(e3);
            ax0 += w0 * bflo(v0); ay0 += w0 * bfhi(v0);
            ax1 += w1 * bflo(v1); ay1 += w1 * bfhi(v1);
            ax0 += w2 * bflo(v2); ay0 += w2 * bfhi(v2);
            ax1 += w3 * bflo(v3); ay1 += w3 * bfhi(v3);
        }
        for (; j < c; ++j) {
            unsigned e = __shfl(pk, j, 64);
            unsigned v = gw2[(size_t)(e & 0xffffu) * 64 + lane];
            float w = bfhi(e);
            ax0 += w * bflo(v); ay0 += w * bfhi(v);
        }
    }
    int c0 = 2 * lane;
    float b0 = (c0 < 64) ? cbv[c0] : cbt[c0 - 64];
    float b1 = (c0 + 1 < 64) ? cbv[c0 + 1] : cbt[c0 + 1 - 64];
    float2 r;
    r.x = b0 + dr * (ax0 + ax1);
    r.y = b1 + dr * (ay0 + ay1);
    *(float2*)(h2 + (size_t)row * 128 + c0) = r;
}

// rep0[row][c] = (row<NUSER ? weight_u[row*2 + c/64] : 1) * (x_br + h2 + h12)
__global__ __launch_bounds__(256) void k_accum_rep(const float* __restrict__ xv, const float* __restrict__ xt,
                                                   const float* __restrict__ h2, const float* __restrict__ h12,
                                                   const float* __restrict__ weight_u, float* __restrict__ rep0) {
    int id = blockIdx.x * 256 + threadIdx.x;
    if (id >= NNODE * 128) return;
    int row = id >> 7, c = id & 127;
    const float* x = (c < 64) ? xv : xt;
    float s = x[(size_t)row * 64 + (c & 63)] + h2[id] + h12[id];
    float w = (row < NUSER) ? weight_u[row * 2 + (c >> 6)] : 1.0f;
    rep0[id] = w * s;
}

__global__ __launch_bounds__(256) void k_user(const float* __restrict__ rep0, const int* __restrict__ ug,
                                              const float* __restrict__ uwm, float* __restrict__ out) {
    int id = blockIdx.x * 256 + threadIdx.x;
    if (id >= NUSER * 128) return;
    int u = id >> 7, d = id & 127;
    float acc = rep0[id];
    #pragma unroll 4
    for (int k = 0; k < KUSER; k++) {
        int nb = ug[u * KUSER + k];
        acc += uwm[u * KUSER + k] * rep0[(size_t)nb * 128 + d];
    }
    out[id] = acc;
}

template<bool ADD_BASE>
__global__ __launch_bounds__(256) void k_item_prop(const float* __restrict__ srcrep, const int* __restrict__ col,
                                                   const float* __restrict__ vals, const float* __restrict__ base,
                                                   float* __restrict__ dstrep) {
    int id = blockIdx.x * 256 + threadIdx.x;
    if (id >= NITEM * 128) return;
    int r = id >> 7, d = id & 127;
    float acc = 0.f;
    #pragma unroll
    for (int j = 0; j < KITEM; j++) {
        int c = col[r * KITEM + j];
        acc += vals[r * KITEM + j] * srcrep[(size_t)c * 128 + d];
    }
    if (ADD_BASE) acc += base[id];
    dstrep[id] = acc;
}

extern "C" void kernel_launch(void* const* d_in, const int* in_sizes, int n_in,
                              void* d_out, int out_size, void* d_ws, size_t ws_size,
                              hipStream_t stream) {
    const int*   edge_index = (const int*)d_in[0];
    const float* v_feat   = (const float*)d_in[1];
    const float* t_feat   = (const float*)d_in[2];
    const float* v_pref   = (const float*)d_in[3];
    const float* t_pref   = (const float*)d_in[4];
    const float* v_mlp1_w = (const float*)d_in[5];
    const float* v_mlp1_b = (const float*)d_in[6];
    const float* v_mlp2_w = (const float*)d_in[7];
    const float* v_mlp2_b = (const float*)d_in[8];
    const float* t_mlp1_w = (const float*)d_in[9];
    const float* t_mlp1_b = (const float*)d_in[10];
    const float* t_mlp2_w = (const float*)d_in[11];
    const float* t_mlp2_b = (const float*)d_in[12];
    const float* v_conv_w = (const float*)d_in[13];
    const float* v_conv_b = (const float*)d_in[14];
    const float* t_conv_w = (const float*)d_in[15];
    const float* t_conv_b = (const float*)d_in[16];
    const float* weight_u = (const float*)d_in[17];
    const int*   user_graph = (const int*)d_in[18];
    const float* uwm      = (const float*)d_in[19];
    const int*   mm_indices = (const int*)d_in[20];
    const float* mm_values  = (const float*)d_in[21];
    float* out = (float*)d_out;

    char* wsb = (char*)d_ws;
    size_t off = 0;
    auto alloc = [&](size_t bytes) -> void* {
        void* p = wsb + off;
        off = (off + bytes + 255) & ~(size_t)255;
        return p;
    };
    int*      cnt     = (int*)     alloc(NNODE * 4);
    float*    dinv    = (float*)   alloc(NNODE * 4);
    int*      rowptr  = (int*)     alloc((NNODE + 1) * 4);
    int*      bsum    = (int*)     alloc(256 * 4);
    int*      cursor  = (int*)     alloc(NNODE * 4);
    unsigned* csr_pkd = (unsigned*)alloc((size_t)2 * NE * 4);
    short*    Btw     = (short*)   alloc((size_t)2048 * 256 * 2);
    short*    W2b     = (short*)   alloc((size_t)256 * 64 * 2);
    float*    xv      = (float*)   alloc((size_t)NNODE * DIM * 4);
    float*    xt      = (float*)   alloc((size_t)NNODE * DIM * 4);
    unsigned short* gw2 = (unsigned short*)alloc((size_t)NNODE * 128 * 2);
    float*    h2      = (float*)   alloc((size_t)NNODE * 128 * 4);
    float*    h12     = (float*)   alloc((size_t)NNODE * 128 * 4);
    float*    rep0    = (float*)   alloc((size_t)NNODE * 128 * 4);
    float*    tmp     = (float*)   alloc((size_t)NITEM * 128 * 4);
    (void)ws_size; (void)n_in; (void)in_sizes; (void)out_size;

    const int* e_src = edge_index;
    const int* e_dst = edge_index + 2 * NE;
    const int* mm_col = mm_indices + NITEM * KITEM;

    const int NB = (NNODE + 255) / 256;   // 235

    // degree + dinv + packed CSR
    hipMemsetAsync(cnt, 0, NNODE * 4, stream);
    k_count<<<(2 * NE + 255) / 256, 256, 0, stream>>>(e_dst, cnt, 2 * NE);
    k_dinv<<<(NNODE + 255) / 256, 256, 0, stream>>>(cnt, dinv);
    k_scanA<<<NB, 256, 0, stream>>>(cnt, rowptr, bsum, NNODE);
    k_scanB<<<1, 256, 0, stream>>>(bsum, NB);
    k_scanC<<<NB, 256, 0, stream>>>(rowptr, bsum, cursor, NNODE);
    k_fill<<<(2 * NE + 255) / 256, 256, 0, stream>>>(e_src, e_dst, dinv, cursor, csr_pkd, 2 * NE);

    // fused MLP per branch (items rows of x)
    {
        dim3 t1(2048 / 16, 16);
        k_transpose_bf16<<<t1, 256, 0, stream>>>(v_mlp1_w, Btw, 2048, 256);
        dim3 t2(256 / 16, 4);
        k_transpose_bf16<<<t2, 256, 0, stream>>>(v_mlp2_w, W2b, 256, 64);
        mlp_fused<<<NITEM / 64, 256, 0, stream>>>(v_feat, Btw, v_mlp1_b, W2b, v_mlp2_b,
                                                  xv + (size_t)NUSER * DIM, 2048);
        dim3 t3(768 / 16, 16);
        k_transpose_bf16<<<t3, 256, 0, stream>>>(t_mlp1_w, Btw, 768, 256);
        k_transpose_bf16<<<t2, 256, 0, stream>>>(t_mlp2_w, W2b, 256, 64);
        mlp_fused<<<NITEM / 64, 256, 0, stream>>>(t_feat, Btw, t_mlp1_b, W2b, t_mlp2_b,
                                                  xt + (size_t)NUSER * DIM, 768);
    }
    // user rows of x: copy pref + l2n (both branches)
    {
        dim3 g(NUSER / 4, 2);
        k_l2n_pref<<<g, 256, 0, stream>>>(v_pref, t_pref, xv, xt);
    }

    // conv layer 1
    {
        dim3 g((NNODE + 63) / 64, 2);
        conv_dual<<<g, 256, 0, stream>>>(xv, xt, DIM, v_conv_w, t_conv_w, gw2);
        k_gather2<<<(NNODE + 3) / 4, 256, 0, stream>>>(rowptr, csr_pkd, dinv, (const unsigned*)gw2,
                                                       v_conv_b, t_conv_b, h2);
        // conv layer 2
        conv_dual<<<g, 256, 0, stream>>>(h2, h2 + 64, 128, v_conv_w, t_conv_w, gw2);
        k_gather2<<<(NNODE + 3) / 4, 256, 0, stream>>>(rowptr, csr_pkd, dinv, (const unsigned*)gw2,
                                                       v_conv_b, t_conv_b, h12);
    }

    // rep0 = weighted (x + h + h1), both branches in one pass
    k_accum_rep<<<(NNODE * 128 + 255) / 256, 256, 0, stream>>>(xv, xt, h2, h12, weight_u, rep0);

    // users
    k_user<<<(NUSER * 128 + 255) / 256, 256, 0, stream>>>(rep0, user_graph, uwm, out);

    // items: 2-layer item-item propagation
    const float* item0 = rep0 + (size_t)NUSER * 128;
    k_item_prop<false><<<(NITEM * 128 + 255) / 256, 256, 0, stream>>>(item0, mm_col, mm_values, nullptr, tmp);
    k_item_prop<true><<<(NITEM * 128 + 255) / 256, 256, 0, stream>>>(tmp, mm_col, mm_values, item0, out + (size_t)NUSER * 128);
}

// Round 7
// 600.188 us; speedup vs baseline: 5.4785x; 1.1026x over previous
//
#include <hip/hip_runtime.h>

#define NUSER 20000
#define NITEM 40000
#define NNODE 60000
#define DIM   64
#define NE    1000000   // per direction; total directed edges = 2*NE
#define KUSER 40
#define KITEM 10

typedef __attribute__((ext_vector_type(8))) short short8v;
typedef __attribute__((ext_vector_type(4))) float floatx4;

__device__ inline short bf16rne(float f) {
    unsigned u = __builtin_bit_cast(unsigned, f);
    unsigned r = (u + 0x7fffu + ((u >> 16) & 1u)) >> 16;
    return (short)r;
}
__device__ inline unsigned cvt_pk_bf16(float lo, float hi) {   // dst.lo16=bf16(lo), dst.hi16=bf16(hi)
    unsigned r;
    asm("v_cvt_pk_bf16_f32 %0, %1, %2" : "=v"(r) : "v"(lo), "v"(hi));
    return r;
}
__device__ inline float bflo(unsigned v) { return __builtin_bit_cast(float, v << 16); }
__device__ inline float bfhi(unsigned v) { return __builtin_bit_cast(float, v & 0xffff0000u); }

// ---------------- degree / norm ----------------
__global__ __launch_bounds__(256) void k_count(const int* __restrict__ dst, int* __restrict__ cnt, int n) {
    int i = blockIdx.x * 256 + threadIdx.x;
    if (i < n) atomicAdd(&cnt[dst[i]], 1);
}

__global__ __launch_bounds__(256) void k_dinv(const int* __restrict__ cnt, float* __restrict__ dinv) {
    int i = blockIdx.x * 256 + threadIdx.x;
    if (i < NNODE) dinv[i] = 1.0f / sqrtf((float)(cnt[i] + 1));  // +1 self loop
}

// ---------------- exclusive scan (3-kernel) ----------------
__global__ __launch_bounds__(256) void k_scanA(const int* __restrict__ v, int* __restrict__ excl,
                                               int* __restrict__ bsum, int n) {
    __shared__ int s[256];
    int t = threadIdx.x, i = blockIdx.x * 256 + t;
    int orig = (i < n) ? v[i] : 0;
    s[t] = orig; __syncthreads();
    #pragma unroll
    for (int off = 1; off < 256; off <<= 1) {
        int u = (t >= off) ? s[t - off] : 0;
        __syncthreads();
        s[t] += u;
        __syncthreads();
    }
    if (i < n) excl[i] = s[t] - orig;
    if (t == 255) bsum[blockIdx.x] = s[255];
}

__global__ __launch_bounds__(256) void k_scanB(int* __restrict__ bsum, int nb) {
    __shared__ int s[256];
    int t = threadIdx.x;
    int orig = (t < nb) ? bsum[t] : 0;
    s[t] = orig; __syncthreads();
    #pragma unroll
    for (int off = 1; off < 256; off <<= 1) {
        int u = (t >= off) ? s[t - off] : 0;
        __syncthreads();
        s[t] += u;
        __syncthreads();
    }
    if (t < nb) bsum[t] = s[t] - orig;  // exclusive
}

__global__ __launch_bounds__(256) void k_scanC(int* __restrict__ excl, const int* __restrict__ bsum,
                                               int* __restrict__ cursor, int n) {
    int i = blockIdx.x * 256 + threadIdx.x;
    if (i < n) {
        int v = excl[i] + bsum[blockIdx.x];
        excl[i] = v;
        cursor[i] = v;
    }
    if (i == 0) excl[n] = 2 * NE;
}

// fill packed CSR: entry = (bf16bits(dinv[src]) << 16) | src   (src < 65536)
__global__ __launch_bounds__(256) void k_fill(const int* __restrict__ src, const int* __restrict__ dst,
                                              const float* __restrict__ dinv, int* __restrict__ cursor,
                                              unsigned* __restrict__ csr_pkd, int n) {
    int i = blockIdx.x * 256 + threadIdx.x;
    if (i >= n) return;
    int s = src[i], d = dst[i];
    unsigned pk = ((unsigned)(unsigned short)bf16rne(dinv[s]) << 16) | (unsigned)s;
    int pos = atomicAdd(&cursor[d], 1);
    csr_pkd[pos] = pk;
}

// ---------------- weight transpose + bf16 cast, k-blocked: Btb[k/32][n][k%32] ----------------
__global__ __launch_bounds__(256) void k_transpose_bf16(const float* __restrict__ B, short* __restrict__ Btb,
                                                        int K, int N) {
    __shared__ float s[16][17];
    int t = threadIdx.x, tx = t & 15, ty = t >> 4;
    int k0 = blockIdx.x * 16, n0 = blockIdx.y * 16;
    s[ty][tx] = B[(size_t)(k0 + ty) * N + n0 + tx];
    __syncthreads();
    int k = k0 + tx, n = n0 + ty;
    Btb[(size_t)(k >> 5) * (N * 32) + n * 32 + (k & 31)] = bf16rne(s[tx][ty]);
}

// ---------------- fused MLP: X = l2n(lrelu(A@W1+b1)@W2+b2), MFMA both GEMMs ----------------
#define AP   40    // LDS row pad (80B, 16B-aligned, 2-way bank alias = free)
#define MIDP 264   // mid row pad (528B, 16B-aligned)
__global__ __launch_bounds__(256) void mlp_fused(const float* __restrict__ A, const short* __restrict__ B1t,
                                                 const float* __restrict__ b1, const short* __restrict__ B2t,
                                                 const float* __restrict__ b2, float* __restrict__ X, int K) {
    __shared__ short smem[2 * 64 * AP + 2 * 256 * AP];
    short* As = smem;                 // [2][64*AP]
    short* Bs = smem + 2 * 64 * AP;   // [2][256*AP]; reused as mid[64][MIDP]
    const int tid = threadIdx.x;
    const int lane = tid & 63, wid = tid >> 6;
    const int rowBase = blockIdx.x * 64;

    const int sar = tid >> 2, sac = (tid & 3) * 8;
    const float* aptr = A + (size_t)(rowBase + sar) * K + sac;

    const int fk = (lane >> 4) * 8;
    const int faoff = (lane & 15) * AP + fk;
    const int fboff = (wid * 64 + (lane & 15)) * AP + fk;

    floatx4 acc[4][4];
    #pragma unroll
    for (int m = 0; m < 4; m++)
        #pragma unroll
        for (int n = 0; n < 4; n++) acc[m][n] = (floatx4)0.f;

    float4 ra0, ra1;
    short8v rb[4];
    const int nk = K >> 5;

    auto ldg = [&](int ks) {
        const float* ap = aptr + ks * 32;
        ra0 = *(const float4*)(ap);
        ra1 = *(const float4*)(ap + 4);
        const short* bsrc = B1t + (size_t)ks * 8192 + tid * 8;
        #pragma unroll
        for (int it = 0; it < 4; it++) rb[it] = *(const short8v*)(bsrc + it * 2048);
    };
    auto stv = [&](int buf) {
        uint4 av;
        av.x = cvt_pk_bf16(ra0.x, ra0.y); av.y = cvt_pk_bf16(ra0.z, ra0.w);
        av.z = cvt_pk_bf16(ra1.x, ra1.y); av.w = cvt_pk_bf16(ra1.z, ra1.w);
        *(uint4*)&As[buf * (64 * AP) + sar * AP + sac] = av;
        #pragma unroll
        for (int it = 0; it < 4; it++)
            *(short8v*)&Bs[buf * (256 * AP) + (sar + it * 64) * AP + sac] = rb[it];
    };

    ldg(0); stv(0);
    __syncthreads();
    int cur = 0;
    for (int ks = 0; ks < nk; ++ks) {
        if (ks + 1 < nk) ldg(ks + 1);
        short8v a[4], b[4];
        #pragma unroll
        for (int m = 0; m < 4; m++) a[m] = *(const short8v*)&As[cur * (64 * AP) + faoff + m * 16 * AP];
        #pragma unroll
        for (int n = 0; n < 4; n++) b[n] = *(const short8v*)&Bs[cur * (256 * AP) + fboff + n * 16 * AP];
        #pragma unroll
        for (int m = 0; m < 4; m++)
            #pragma unroll
            for (int n = 0; n < 4; n++)
                acc[m][n] = __builtin_amdgcn_mfma_f32_16x16x32_bf16(a[m], b[n], acc[m][n], 0, 0, 0);
        if (ks + 1 < nk) stv(cur ^ 1);
        __syncthreads();
        cur ^= 1;
    }

    // phase 2: bias + lrelu -> bf16 mid in LDS (C/D layout: col=lane&15, row=(lane>>4)*4+q)
    short* mid = Bs;
    float bcol[4];
    #pragma unroll
    for (int n = 0; n < 4; n++) bcol[n] = b1[wid * 64 + n * 16 + (lane & 15)];
    #pragma unroll
    for (int m = 0; m < 4; m++)
        #pragma unroll
        for (int n = 0; n < 4; n++)
            #pragma unroll
            for (int q = 0; q < 4; q++) {
                int row = m * 16 + (lane >> 4) * 4 + q;
                int col = wid * 64 + n * 16 + (lane & 15);
                float v = acc[m][n][q] + bcol[n];
                v = v > 0.f ? v : 0.01f * v;
                mid[row * MIDP + col] = bf16rne(v);
            }
    __syncthreads();

    // phase 3: temp = mid @ W2 (wave wid owns rows wid*16..wid*16+15)
    floatx4 acc2[4];
    #pragma unroll
    for (int n2 = 0; n2 < 4; n2++) acc2[n2] = (floatx4)0.f;
    const int arow = wid * 16 + (lane & 15);
    #pragma unroll
    for (int ks2 = 0; ks2 < 8; ++ks2) {
        short8v af = *(const short8v*)&mid[arow * MIDP + ks2 * 32 + fk];
        const short* bp = B2t + ks2 * 2048 + fk;
        short8v bf4[4];
        #pragma unroll
        for (int n2 = 0; n2 < 4; n2++) bf4[n2] = *(const short8v*)(bp + (n2 * 16 + (lane & 15)) * 32);
        #pragma unroll
        for (int n2 = 0; n2 < 4; n2++)
            acc2[n2] = __builtin_amdgcn_mfma_f32_16x16x32_bf16(af, bf4[n2], acc2[n2], 0, 0, 0);
    }

    // phase 4: bias + row-L2-norm in-register, write X
    float b2c[4];
    #pragma unroll
    for (int n2 = 0; n2 < 4; n2++) b2c[n2] = b2[n2 * 16 + (lane & 15)];
    #pragma unroll
    for (int q = 0; q < 4; ++q) {
        float v[4]; float ss = 0.f;
        #pragma unroll
        for (int n2 = 0; n2 < 4; n2++) { v[n2] = acc2[n2][q] + b2c[n2]; ss += v[n2] * v[n2]; }
        ss += __shfl_xor(ss, 1, 64);
        ss += __shfl_xor(ss, 2, 64);
        ss += __shfl_xor(ss, 4, 64);
        ss += __shfl_xor(ss, 8, 64);
        float sc = 1.f / fmaxf(sqrtf(ss), 1e-12f);
        int grow = rowBase + wid * 16 + (lane >> 4) * 4 + q;
        #pragma unroll
        for (int n2 = 0; n2 < 4; n2++)
            X[(size_t)grow * 64 + n2 * 16 + (lane & 15)] = v[n2] * sc;
    }
}

// ---------------- pref rows: copy + L2-normalize (both branches) ----------------
__global__ __launch_bounds__(256) void k_l2n_pref(const float* __restrict__ prefv, const float* __restrict__ preft,
                                                  float* __restrict__ xv, float* __restrict__ xt) {
    int row = blockIdx.x * 4 + (threadIdx.x >> 6);
    int lane = threadIdx.x & 63;
    if (row >= NUSER) return;
    const float* p = blockIdx.y ? preft : prefv;
    float* x = blockIdx.y ? xt : xv;
    float v = p[(size_t)row * 64 + lane];
    float ss = v * v;
    #pragma unroll
    for (int off = 32; off >= 1; off >>= 1) ss += __shfl_xor(ss, off, 64);
    x[(size_t)row * 64 + lane] = v / fmaxf(sqrtf(ss), 1e-12f);
}

// ---------------- dual-branch conv GEMM: Ch[row][z*64 + c] = bf16(A_z[row] @ B_z), K=N=64 ----------------
__global__ __launch_bounds__(256) void conv_dual(const float* __restrict__ A0, const float* __restrict__ A1,
                                                 int lda, const float* __restrict__ Bv, const float* __restrict__ Bt2,
                                                 unsigned short* __restrict__ Ch) {
    __shared__ float As2[16][65];
    __shared__ float Bs2[16][65];
    const float* A = blockIdx.y ? A1 : A0;
    const float* B = blockIdx.y ? Bt2 : Bv;
    const int colOff = (int)blockIdx.y * 64;
    const int tid = threadIdx.x;
    const int tx = tid & 15, ty = tid >> 4;
    const int rowBase = blockIdx.x * 64;
    float acc[4][4] = {};
    for (int k0 = 0; k0 < 64; k0 += 16) {
        {
            int r = tid >> 2, c = (tid & 3) * 4;
            int gr = rowBase + r;
            float4 v = make_float4(0.f, 0.f, 0.f, 0.f);
            if (gr < NNODE) v = *(const float4*)(A + (size_t)gr * lda + k0 + c);
            As2[c + 0][r] = v.x; As2[c + 1][r] = v.y; As2[c + 2][r] = v.z; As2[c + 3][r] = v.w;
        }
        {
            int r = tid >> 4, c = (tid & 15) * 4;
            float4 v = *(const float4*)(B + (size_t)(k0 + r) * 64 + c);
            Bs2[r][c + 0] = v.x; Bs2[r][c + 1] = v.y; Bs2[r][c + 2] = v.z; Bs2[r][c + 3] = v.w;
        }
        __syncthreads();
        #pragma unroll
        for (int k = 0; k < 16; k++) {
            float a[4], b[4];
            #pragma unroll
            for (int i = 0; i < 4; i++) a[i] = As2[k][ty * 4 + i];
            #pragma unroll
            for (int j = 0; j < 4; j++) b[j] = Bs2[k][tx * 4 + j];
            #pragma unroll
            for (int i = 0; i < 4; i++)
                #pragma unroll
                for (int j = 0; j < 4; j++) acc[i][j] += a[i] * b[j];
        }
        __syncthreads();
    }
    const int gr0 = rowBase + ty * 4, gc = tx * 4;
    #pragma unroll
    for (int i = 0; i < 4; i++) {
        if (gr0 + i >= NNODE) break;
        uint2 hh;
        hh.x = cvt_pk_bf16(acc[i][0], acc[i][1]);
        hh.y = cvt_pk_bf16(acc[i][2], acc[i][3]);
        *(uint2*)(Ch + (size_t)(gr0 + i) * 128 + colOff + gc) = hh;
    }
}

// ---------------- gather body (shared by layer1 / layer2) ----------------
__device__ inline float2 gather_row(const int* rowptr, const unsigned* csr_pkd, const unsigned* gw2,
                                    int row, int lane, float dr) {
    int p0 = rowptr[row], p1 = rowptr[row + 1];
    unsigned sv = gw2[(size_t)row * 64 + lane];
    float ax0 = dr * bflo(sv), ay0 = dr * bfhi(sv);
    float ax1 = 0.f, ay1 = 0.f;
    for (int p = p0; p < p1; p += 64) {
        int c = p1 - p; if (c > 64) c = 64;
        unsigned pk = (lane < c) ? csr_pkd[p + lane] : 0u;
        int j = 0;
        for (; j + 4 <= c; j += 4) {
            unsigned e0 = __shfl(pk, j, 64),     e1 = __shfl(pk, j + 1, 64);
            unsigned e2 = __shfl(pk, j + 2, 64), e3 = __shfl(pk, j + 3, 64);
            unsigned v0 = gw2[(size_t)(e0 & 0xffffu) * 64 + lane];
            unsigned v1 = gw2[(size_t)(e1 & 0xffffu) * 64 + lane];
            unsigned v2 = gw2[(size_t)(e2 & 0xffffu) * 64 + lane];
            unsigned v3 = gw2[(size_t)(e3 & 0xffffu) * 64 + lane];
            float w0 = bfhi(e0), w1 = bfhi(e1), w2 = bfhi(e2), w3 = bfhi(e3);
            ax0 += w0 * bflo(v0); ay0 += w0 * bfhi(v0);
            ax1 += w1 * bflo(v1); ay1 += w1 * bfhi(v1);
            ax0 += w2 * bflo(v2); ay0 += w2 * bfhi(v2);
            ax1 += w3 * bflo(v3); ay1 += w3 * bfhi(v3);
        }
        for (; j < c; ++j) {
            unsigned e = __shfl(pk, j, 64);
            unsigned v = gw2[(size_t)(e & 0xffffu) * 64 + lane];
            float w = bfhi(e);
            ax0 += w * bflo(v); ay0 += w * bfhi(v);
        }
    }
    float2 r; r.x = ax0 + ax1; r.y = ay0 + ay1;
    return r;
}

// layer 1: h2[row][c] = cb(c) + dr*(...)
__global__ __launch_bounds__(256) void k_gather2(const int* __restrict__ rowptr, const unsigned* __restrict__ csr_pkd,
                                                 const float* __restrict__ dinv, const unsigned* __restrict__ gw2,
                                                 const float* __restrict__ cbv, const float* __restrict__ cbt,
                                                 float* __restrict__ h2) {
    int row = blockIdx.x * 4 + (threadIdx.x >> 6);
    int lane = threadIdx.x & 63;
    if (row >= NNODE) return;
    float dr = dinv[row];
    float2 g = gather_row(rowptr, csr_pkd, gw2, row, lane, dr);
    int c0 = 2 * lane;
    float b0 = (c0 < 64) ? cbv[c0] : cbt[c0 - 64];
    float b1 = (c0 + 1 < 64) ? cbv[c0 + 1] : cbt[c0 + 1 - 64];
    float2 r;
    r.x = b0 + dr * g.x;
    r.y = b1 + dr * g.y;
    *(float2*)(h2 + (size_t)row * 128 + c0) = r;
}

// layer 2 fused with rep accumulation:
// h12 = cb + dr*gather;  rep = w_u * (x + h2 + h12);  write rep0 (f32) + rep_bf (2xbf16)
__global__ __launch_bounds__(256) void k_gather2_rep(const int* __restrict__ rowptr, const unsigned* __restrict__ csr_pkd,
                                                     const float* __restrict__ dinv, const unsigned* __restrict__ gw2,
                                                     const float* __restrict__ cbv, const float* __restrict__ cbt,
                                                     const float* __restrict__ xv, const float* __restrict__ xt,
                                                     const float* __restrict__ h2, const float* __restrict__ weight_u,
                                                     float* __restrict__ rep0, unsigned* __restrict__ rep_bf) {
    int row = blockIdx.x * 4 + (threadIdx.x >> 6);
    int lane = threadIdx.x & 63;
    if (row >= NNODE) return;
    float dr = dinv[row];
    float2 g = gather_row(rowptr, csr_pkd, gw2, row, lane, dr);
    int c0 = 2 * lane;
    float b0 = (c0 < 64) ? cbv[c0] : cbt[c0 - 64];
    float b1 = (c0 + 1 < 64) ? cbv[c0 + 1] : cbt[c0 + 1 - 64];
    float h12x = b0 + dr * g.x;
    float h12y = b1 + dr * g.y;
    const float* x = (lane < 32) ? xv : xt;
    float2 xp = *(const float2*)(x + (size_t)row * 64 + (c0 & 63));
    float2 hp = *(const float2*)(h2 + (size_t)row * 128 + c0);
    float w = (row < NUSER) ? weight_u[row * 2 + (lane >> 5)] : 1.0f;
    float2 rp;
    rp.x = w * (xp.x + hp.x + h12x);
    rp.y = w * (xp.y + hp.y + h12y);
    *(float2*)(rep0 + (size_t)row * 128 + c0) = rp;
    rep_bf[(size_t)row * 64 + lane] = cvt_pk_bf16(rp.x, rp.y);
}

// fused: user aggregation + item-item layer 1 (both read rep_bf, independent)
#define UBLK (NUSER * 64 / 256)   // 5000
__global__ __launch_bounds__(256) void k_user_item1(const float* __restrict__ rep0, const unsigned* __restrict__ rep_bf,
                                                    const int* __restrict__ ug, const float* __restrict__ uwm,
                                                    const int* __restrict__ mm_col, const float* __restrict__ mm_values,
                                                    float* __restrict__ out, unsigned* __restrict__ tmp_bf) {
    int bid = blockIdx.x;
    if (bid < UBLK) {
        int id = bid * 256 + threadIdx.x;
        int u = id >> 6, lane = id & 63;
        float2 acc = *(const float2*)(rep0 + (size_t)u * 128 + 2 * lane);   // self, f32-exact
        #pragma unroll 4
        for (int k = 0; k < KUSER; k++) {
            int nb = ug[u * KUSER + k];
            float w = uwm[u * KUSER + k];
            unsigned v = rep_bf[(size_t)nb * 64 + lane];
            acc.x += w * bflo(v);
            acc.y += w * bfhi(v);
        }
        *(float2*)(out + (size_t)u * 128 + 2 * lane) = acc;
    } else {
        int id = (bid - UBLK) * 256 + threadIdx.x;
        int r = id >> 6, lane = id & 63;
        float ax = 0.f, ay = 0.f;
        #pragma unroll
        for (int j = 0; j < KITEM; j++) {
            int c = mm_col[r * KITEM + j];
            float w = mm_values[r * KITEM + j];
            unsigned v = rep_bf[(size_t)(NUSER + c) * 64 + lane];
            ax += w * bflo(v);
            ay += w * bfhi(v);
        }
        tmp_bf[(size_t)r * 64 + lane] = cvt_pk_bf16(ax, ay);
    }
}

// item-item layer 2: out[NUSER+r] = rep0[NUSER+r] + gather(tmp_bf)   (out = FULL out pointer)
__global__ __launch_bounds__(256) void k_item2(const float* __restrict__ rep0, const unsigned* __restrict__ tmp_bf,
                                               const int* __restrict__ mm_col, const float* __restrict__ mm_values,
                                               float* __restrict__ out) {
    int id = blockIdx.x * 256 + threadIdx.x;
    int r = id >> 6, lane = id & 63;
    if (r >= NITEM) return;
    float ax = 0.f, ay = 0.f;
    #pragma unroll
    for (int j = 0; j < KITEM; j++) {
        int c = mm_col[r * KITEM + j];
        float w = mm_values[r * KITEM + j];
        unsigned v = tmp_bf[(size_t)c * 64 + lane];
        ax += w * bflo(v);
        ay += w * bfhi(v);
    }
    float2 base = *(const float2*)(rep0 + (size_t)(NUSER + r) * 128 + 2 * lane);
    float2 o;
    o.x = base.x + ax;
    o.y = base.y + ay;
    *(float2*)(out + (size_t)(NUSER + r) * 128 + 2 * lane) = o;
}

extern "C" void kernel_launch(void* const* d_in, const int* in_sizes, int n_in,
                              void* d_out, int out_size, void* d_ws, size_t ws_size,
                              hipStream_t stream) {
    const int*   edge_index = (const int*)d_in[0];
    const float* v_feat   = (const float*)d_in[1];
    const float* t_feat   = (const float*)d_in[2];
    const float* v_pref   = (const float*)d_in[3];
    const float* t_pref   = (const float*)d_in[4];
    const float* v_mlp1_w = (const float*)d_in[5];
    const float* v_mlp1_b = (const float*)d_in[6];
    const float* v_mlp2_w = (const float*)d_in[7];
    const float* v_mlp2_b = (const float*)d_in[8];
    const float* t_mlp1_w = (const float*)d_in[9];
    const float* t_mlp1_b = (const float*)d_in[10];
    const float* t_mlp2_w = (const float*)d_in[11];
    const float* t_mlp2_b = (const float*)d_in[12];
    const float* v_conv_w = (const float*)d_in[13];
    const float* v_conv_b = (const float*)d_in[14];
    const float* t_conv_w = (const float*)d_in[15];
    const float* t_conv_b = (const float*)d_in[16];
    const float* weight_u = (const float*)d_in[17];
    const int*   user_graph = (const int*)d_in[18];
    const float* uwm      = (const float*)d_in[19];
    const int*   mm_indices = (const int*)d_in[20];
    const float* mm_values  = (const float*)d_in[21];
    float* out = (float*)d_out;

    char* wsb = (char*)d_ws;
    size_t off = 0;
    auto alloc = [&](size_t bytes) -> void* {
        void* p = wsb + off;
        off = (off + bytes + 255) & ~(size_t)255;
        return p;
    };
    int*      cnt     = (int*)     alloc(NNODE * 4);
    float*    dinv    = (float*)   alloc(NNODE * 4);
    int*      rowptr  = (int*)     alloc((NNODE + 1) * 4);
    int*      bsum    = (int*)     alloc(256 * 4);
    int*      cursor  = (int*)     alloc(NNODE * 4);
    unsigned* csr_pkd = (unsigned*)alloc((size_t)2 * NE * 4);
    short*    Btw     = (short*)   alloc((size_t)2048 * 256 * 2);
    short*    W2b     = (short*)   alloc((size_t)256 * 64 * 2);
    float*    xv      = (float*)   alloc((size_t)NNODE * DIM * 4);
    float*    xt      = (float*)   alloc((size_t)NNODE * DIM * 4);
    unsigned short* gw2 = (unsigned short*)alloc((size_t)NNODE * 128 * 2);
    float*    h2      = (float*)   alloc((size_t)NNODE * 128 * 4);
    float*    rep0    = (float*)   alloc((size_t)NNODE * 128 * 4);
    unsigned* rep_bf  = (unsigned*)alloc((size_t)NNODE * 64 * 4);
    unsigned* tmp_bf  = (unsigned*)alloc((size_t)NITEM * 64 * 4);
    (void)ws_size; (void)n_in; (void)in_sizes; (void)out_size;

    const int* e_src = edge_index;
    const int* e_dst = edge_index + 2 * NE;
    const int* mm_col = mm_indices + NITEM * KITEM;

    const int NB = (NNODE + 255) / 256;   // 235

    // degree + dinv + packed CSR
    hipMemsetAsync(cnt, 0, NNODE * 4, stream);
    k_count<<<(2 * NE + 255) / 256, 256, 0, stream>>>(e_dst, cnt, 2 * NE);
    k_dinv<<<(NNODE + 255) / 256, 256, 0, stream>>>(cnt, dinv);
    k_scanA<<<NB, 256, 0, stream>>>(cnt, rowptr, bsum, NNODE);
    k_scanB<<<1, 256, 0, stream>>>(bsum, NB);
    k_scanC<<<NB, 256, 0, stream>>>(rowptr, bsum, cursor, NNODE);
    k_fill<<<(2 * NE + 255) / 256, 256, 0, stream>>>(e_src, e_dst, dinv, cursor, csr_pkd, 2 * NE);

    // fused MLP per branch (items rows of x)
    {
        dim3 t1(2048 / 16, 16);
        k_transpose_bf16<<<t1, 256, 0, stream>>>(v_mlp1_w, Btw, 2048, 256);
        dim3 t2(256 / 16, 4);
        k_transpose_bf16<<<t2, 256, 0, stream>>>(v_mlp2_w, W2b, 256, 64);
        mlp_fused<<<NITEM / 64, 256, 0, stream>>>(v_feat, Btw, v_mlp1_b, W2b, v_mlp2_b,
                                                  xv + (size_t)NUSER * DIM, 2048);
        dim3 t3(768 / 16, 16);
        k_transpose_bf16<<<t3, 256, 0, stream>>>(t_mlp1_w, Btw, 768, 256);
        k_transpose_bf16<<<t2, 256, 0, stream>>>(t_mlp2_w, W2b, 256, 64);
        mlp_fused<<<NITEM / 64, 256, 0, stream>>>(t_feat, Btw, t_mlp1_b, W2b, t_mlp2_b,
                                                  xt + (size_t)NUSER * DIM, 768);
    }
    // user rows of x: copy pref + l2n (both branches)
    {
        dim3 g(NUSER / 4, 2);
        k_l2n_pref<<<g, 256, 0, stream>>>(v_pref, t_pref, xv, xt);
    }

    // conv layer 1 + layer 2 (layer 2 fused with rep accumulation)
    {
        dim3 g((NNODE + 63) / 64, 2);
        conv_dual<<<g, 256, 0, stream>>>(xv, xt, DIM, v_conv_w, t_conv_w, gw2);
        k_gather2<<<(NNODE + 3) / 4, 256, 0, stream>>>(rowptr, csr_pkd, dinv, (const unsigned*)gw2,
                                                       v_conv_b, t_conv_b, h2);
        conv_dual<<<g, 256, 0, stream>>>(h2, h2 + 64, 128, v_conv_w, t_conv_w, gw2);
        k_gather2_rep<<<(NNODE + 3) / 4, 256, 0, stream>>>(rowptr, csr_pkd, dinv, (const unsigned*)gw2,
                                                           v_conv_b, t_conv_b, xv, xt, h2, weight_u,
                                                           rep0, rep_bf);
    }

    // users + item layer 1 (one grid), then item layer 2
    k_user_item1<<<UBLK + NITEM * 64 / 256, 256, 0, stream>>>(rep0, rep_bf, user_graph, uwm,
                                                              mm_col, mm_values, out, tmp_bf);
    k_item2<<<NITEM * 64 / 256, 256, 0, stream>>>(rep0, tmp_bf, mm_col, mm_values, out);
}